// Round 3
// baseline (526.036 us; speedup 1.0000x reference)
//
#include <hip/hip_runtime.h>
#include <math.h>

#define BZc 8
#define Cc 512
#define C2c 256
#define HWc 4096
#define OUTC 768
#define NP 1024
#define NQ 3072
#define QG 8        // q groups (chunks) for gemm
#define TAU 5e-5f

typedef _Float16 h8 __attribute__((ext_vector_type(8)));
typedef float f16v __attribute__((ext_vector_type(16)));
typedef float f32x4 __attribute__((ext_vector_type(4)));

// ---------------- K0: build compacted index lists + inverse map + zero counters --
__global__ __launch_bounds__(1024) void k_build(const int* __restrict__ mask,
                                                int* __restrict__ pidx,
                                                int* __restrict__ qidx,
                                                int* __restrict__ qinv,
                                                int* __restrict__ cnt) {
    __shared__ int s0[1024], s1[1024], t0[1024], t1[1024];
    int t = threadIdx.x;
    if (t < 8) cnt[t] = 0;
    int f[4];
    int cp = 0;
#pragma unroll
    for (int j = 0; j < 4; ++j) { f[j] = mask[t * 4 + j]; cp += f[j]; }
    s0[t] = cp; s1[t] = 4 - cp;
    __syncthreads();
    int *a = s0, *b = s1, *c = t0, *d = t1;
    for (int off = 1; off < 1024; off <<= 1) {
        int vp = a[t] + (t >= off ? a[t - off] : 0);
        int vq = b[t] + (t >= off ? b[t - off] : 0);
        c[t] = vp; d[t] = vq;
        __syncthreads();
        int* tmp;
        tmp = a; a = c; c = tmp;
        tmp = b; b = d; d = tmp;
    }
    int ep = a[t] - cp;
    int eq = b[t] - (4 - cp);
#pragma unroll
    for (int j = 0; j < 4; ++j) {
        int idx = t * 4 + j;
        if (f[j]) { pidx[ep] = idx; qinv[idx] = -1; ep++; }
        else      { qidx[eq] = idx; qinv[idx] = eq; eq++; }
    }
}

// ---------------- K1: prep — transpose + fp16 hi/lo split (latter & former) ------
// blocks 0..511: latter (b = id>>6, 64 q each); 512..639: former (b=(id-512)>>4, 64 p each)
__global__ __launch_bounds__(256) void k_prep(const float* __restrict__ x,
                                              const int* __restrict__ pidx,
                                              const int* __restrict__ qinv,
                                              _Float16* __restrict__ latH,
                                              _Float16* __restrict__ latL,
                                              _Float16* __restrict__ forH,
                                              _Float16* __restrict__ forL,
                                              float* __restrict__ invn,
                                              float* __restrict__ nrm) {
    int id = blockIdx.x;
    bool isLat = id < 512;
    int b  = isLat ? (id >> 6) : ((id - 512) >> 4);
    int bx = isLat ? (id & 63) : ((id - 512) & 15);
    int tid = threadIdx.x;
    __shared__ float tile[64][65];
    __shared__ float sqa[4][64];
    __shared__ float sinv[64];
    __shared__ int rowm[64];    // dest compact row (or -1)
    __shared__ int rowsrc[64];  // source spatial index
    if (tid < 64) {
        if (isLat) { int q = bx * 64 + tid; rowsrc[tid] = q; rowm[tid] = qinv[q]; }
        else       { int pc = bx * 64 + tid; rowsrc[tid] = pidx[pc]; rowm[tid] = pc; }
    }
    __syncthreads();
    const float* xb = x + (size_t)b * Cc * HWc + (isLat ? (size_t)C2c * HWc : 0);
    if (isLat) {
        float sacc = 0.f;
        for (int c0 = 0; c0 < 256; c0 += 64) {
            for (int it = 0; it < 16; ++it) {
                int i = tid + it * 256; int cc = i >> 6, qq = i & 63;
                float v = xb[(size_t)(c0 + cc) * HWc + rowsrc[qq]];
                sacc += v * v;   // qq == tid&63 constant per thread
            }
        }
        sqa[tid >> 6][tid & 63] = sacc;
        __syncthreads();
        if (tid < 64) {
            float s = sqa[0][tid] + sqa[1][tid] + sqa[2][tid] + sqa[3][tid];
            float nr = sqrtf(s) + 1e-8f;
            float inv = 1.0f / nr;
            int q = bx * 64 + tid;
            invn[b * HWc + q] = inv; nrm[b * HWc + q] = nr;
            sinv[tid] = inv;
        }
        __syncthreads();
    }
    _Float16* dH = isLat ? latH + (size_t)b * NQ * 256 : forH + (size_t)b * NP * 256;
    _Float16* dL = isLat ? latL + (size_t)b * NQ * 256 : forL + (size_t)b * NP * 256;
    for (int c0 = 0; c0 < 256; c0 += 64) {
        for (int it = 0; it < 16; ++it) {
            int i = tid + it * 256; int cc = i >> 6, qq = i & 63;
            tile[qq][cc] = xb[(size_t)(c0 + cc) * HWc + rowsrc[qq]];
        }
        __syncthreads();
        int qq = tid >> 2, sub = tid & 3;
        int dr = rowm[qq];
        if (dr >= 0) {
            float scale = isLat ? sinv[qq] : 1.0f;
            h8 hv0, hv1, lv0, lv1;
#pragma unroll
            for (int j = 0; j < 8; ++j) {
                float v = tile[qq][sub * 16 + j] * scale;
                _Float16 h = (_Float16)v;
                hv0[j] = h; lv0[j] = (_Float16)((v - (float)h) * 2048.0f);
            }
#pragma unroll
            for (int j = 0; j < 8; ++j) {
                float v = tile[qq][sub * 16 + 8 + j] * scale;
                _Float16 h = (_Float16)v;
                hv1[j] = h; lv1[j] = (_Float16)((v - (float)h) * 2048.0f);
            }
            size_t o = (size_t)dr * 256 + c0 + sub * 16;
            *(h8*)(dH + o) = hv0; *(h8*)(dH + o + 8) = hv1;
            *(h8*)(dL + o) = lv0; *(h8*)(dL + o + 8) = lv1;
        }
        __syncthreads();
    }
}

// ---------------- K2: MFMA fp16x2 GEMM + per-chunk top-2 -------------------------
// D[q][p] = latter x former^T ; wave owns 32 p cols x 384 q (12 tiles of 32)
__global__ __launch_bounds__(512, 2) void k_gemm(const _Float16* __restrict__ latH,
                                                 const _Float16* __restrict__ latL,
                                                 const _Float16* __restrict__ forH,
                                                 const _Float16* __restrict__ forL,
                                                 float* __restrict__ bv1,
                                                 int* __restrict__ bi1,
                                                 float* __restrict__ bv2) {
    int pg = blockIdx.x;   // 0..3 (256 p each)
    int qg = blockIdx.y;   // 0..7 (384 q each)
    int b  = blockIdx.z;
    int tid = threadIdx.x;
    int w = tid >> 6, lane = tid & 63;
    int l31 = lane & 31, lh = lane >> 5;

    __shared__ __align__(16) _Float16 sH[2][32 * 256];  // 16KB per buf
    __shared__ __align__(16) _Float16 sL[2][32 * 256];

    // ---- former fragments in registers: my wave's 32 p-rows, all K=256 ----
    size_t fo = ((size_t)(b * NP + pg * 256 + w * 32 + l31)) * 256 + lh * 8;
    const _Float16* fH = forH + fo;
    const _Float16* fL = forL + fo;
    h8 BH[16], BL[16];
#pragma unroll
    for (int ks = 0; ks < 16; ++ks) {
        BH[ks] = *(const h8*)(fH + ks * 16);
        BL[ks] = *(const h8*)(fL + ks * 16);
    }

    const _Float16* latHb = latH + (size_t)(b * NQ + qg * 384) * 256;
    const _Float16* latLb = latL + (size_t)(b * NQ + qg * 384) * 256;
    int sq0 = tid >> 5;          // 0..15
    int sq1 = 16 + (tid >> 5);
    int ssl = tid & 31;

    float v1 = -INFINITY, v2 = -INFINITY; int i1 = 0;

    f32x4 rH0, rH1, rL0, rL1;
#define LOADQ(t)                                                                   \
    rH0 = *(const f32x4*)(latHb + ((size_t)((t) * 32 + sq0) * 256 + ssl * 8));     \
    rH1 = *(const f32x4*)(latHb + ((size_t)((t) * 32 + sq1) * 256 + ssl * 8));     \
    rL0 = *(const f32x4*)(latLb + ((size_t)((t) * 32 + sq0) * 256 + ssl * 8));     \
    rL1 = *(const f32x4*)(latLb + ((size_t)((t) * 32 + sq1) * 256 + ssl * 8));
#define WRITEQ(bf)                                                                 \
    *(f32x4*)(&sH[bf][sq0 * 256 + ((ssl ^ sq0) * 8)]) = rH0;                       \
    *(f32x4*)(&sH[bf][sq1 * 256 + ((ssl ^ sq1) * 8)]) = rH1;                       \
    *(f32x4*)(&sL[bf][sq0 * 256 + ((ssl ^ sq0) * 8)]) = rL0;                       \
    *(f32x4*)(&sL[bf][sq1 * 256 + ((ssl ^ sq1) * 8)]) = rL1;

    LOADQ(0); WRITEQ(0);
    __syncthreads();

    for (int t = 0; t < 12; ++t) {
        if (t < 11) { LOADQ(t + 1); }
        const _Float16* bufH = &sH[t & 1][0];
        const _Float16* bufL = &sL[t & 1][0];
        f16v accA = {}, accB = {};
#pragma unroll
        for (int ks = 0; ks < 16; ++ks) {
            int slotA = (ks * 2 + lh) ^ l31;
            h8 aH = *(const h8*)(bufH + l31 * 256 + slotA * 8);
            h8 aL = *(const h8*)(bufL + l31 * 256 + slotA * 8);
            accA = __builtin_amdgcn_mfma_f32_32x32x16_f16(aH, BH[ks], accA, 0, 0, 0);
            accB = __builtin_amdgcn_mfma_f32_32x32x16_f16(aH, BL[ks], accB, 0, 0, 0);
            accB = __builtin_amdgcn_mfma_f32_32x32x16_f16(aL, BH[ks], accB, 0, 0, 0);
        }
        int q0 = qg * 384 + t * 32;
#pragma unroll
        for (int r = 0; r < 16; ++r) {
            float v = accA[r] + accB[r] * (1.0f / 2048.0f);
            int q = q0 + (r & 3) + 8 * (r >> 2) + 4 * lh;
            if (v > v1) { v2 = v1; v1 = v; i1 = q; }
            else if (v > v2) { v2 = v; }
        }
        if (t < 11) { WRITEQ((t + 1) & 1); }
        __syncthreads();
    }
#undef LOADQ
#undef WRITEQ
    // merge lane l with l+32 (same p column)
    float ov1 = __shfl_xor(v1, 32);
    int   oi1 = __shfl_xor(i1, 32);
    float ov2 = __shfl_xor(v2, 32);
    if (ov1 > v1) { v2 = fmaxf(v1, ov2); v1 = ov1; i1 = oi1; }
    else          { v2 = fmaxf(ov1, v2); }
    if (lane < 32) {
        size_t o = ((size_t)b * NP + pg * 256 + w * 32 + lane) * QG + qg;
        bv1[o] = v1; bi1[o] = i1; bv2[o] = v2;
    }
}

// ---------------- K3: merge chunks -> best index + margin flag -------------------
__global__ void k_reduce(const float* __restrict__ bv1, const int* __restrict__ bi1,
                         const float* __restrict__ bv2, int* __restrict__ bfin,
                         int* __restrict__ cnt, int* __restrict__ fixrows) {
    int t = blockIdx.x * blockDim.x + threadIdx.x;
    if (t >= BZc * NP) return;
    float V1 = -INFINITY, V2 = -INFINITY; int I1 = 0;
    for (int c = 0; c < QG; ++c) {
        float a = bv1[(size_t)t * QG + c];
        float a2 = bv2[(size_t)t * QG + c];
        int   i = bi1[(size_t)t * QG + c];
        if (a > V1) { V2 = fmaxf(V1, a2); V1 = a; I1 = i; }
        else        { V2 = fmaxf(V2, a); }
    }
    bfin[t] = I1;
    if (V1 - V2 < TAU) {
        int b = t >> 10;
        int s = atomicAdd(&cnt[b], 1);
        if (s < 32) fixrows[b * 32 + s] = t & 1023;
    }
}

// ---------------- K4: exact fp32 fixup for near-tie rows -------------------------
__global__ __launch_bounds__(256) void k_fixup(const float* __restrict__ x,
                                               const int* __restrict__ pidx,
                                               const int* __restrict__ qidx,
                                               const float* __restrict__ invn,
                                               const int* __restrict__ cnt,
                                               const int* __restrict__ fixrows,
                                               int* __restrict__ bfin) {
    int b = blockIdx.y, s = blockIdx.x;
    int n = cnt[b]; if (n > 32) n = 32;
    if (s >= n) return;
    int p = fixrows[b * 32 + s];
    int porig = pidx[p];
    int tid = threadIdx.x;
    __shared__ float fv[256];
    fv[tid] = x[((size_t)b * Cc + tid) * HWc + porig];
    __syncthreads();
    float acc[12]; int qi[12];
#pragma unroll
    for (int j = 0; j < 12; ++j) { acc[j] = 0.f; qi[j] = qidx[tid + 256 * j]; }
    const float* lx = x + ((size_t)b * Cc + C2c) * HWc;
    for (int c = 0; c < 256; ++c) {
        float f = fv[c];
#pragma unroll
        for (int j = 0; j < 12; ++j)
            acc[j] = fmaf(f, lx[(size_t)c * HWc + qi[j]], acc[j]);
    }
    float bv = -INFINITY; int bq = 1 << 30;
#pragma unroll
    for (int j = 0; j < 12; ++j) {
        float v = acc[j] * invn[b * HWc + qi[j]];
        int q = tid + 256 * j;
        if (v > bv || (v == bv && q < bq)) { bv = v; bq = q; }
    }
    __shared__ float rv[256]; __shared__ int rq[256];
    rv[tid] = bv; rq[tid] = bq; __syncthreads();
    for (int off = 128; off > 0; off >>= 1) {
        if (tid < off) {
            float v = rv[tid + off]; int q = rq[tid + off];
            if (v > rv[tid] || (v == rv[tid] && q < rq[tid])) { rv[tid] = v; rq[tid] = q; }
        }
        __syncthreads();
    }
    if (tid == 0) bfin[b * NP + p] = rq[0];
}

// ---------------- K5: out[:, :512] = x ; out[:, 512:] = 0 ------------------------
__global__ __launch_bounds__(256) void k_fill(const float* __restrict__ x,
                                              float* __restrict__ out) {
    size_t i4 = (size_t)blockIdx.x * blockDim.x + threadIdx.x;
    size_t total4 = (size_t)BZc * OUTC * HWc / 4;
    if (i4 >= total4) return;
    size_t e   = i4 * 4;
    size_t per = (size_t)OUTC * HWc;
    size_t b   = e / per;
    size_t rem = e % per;
    int ch = (int)(rem / HWc);
    float4* o4 = (float4*)out;
    if (ch < Cc) {
        const float4* x4 = (const float4*)x;
        o4[i4] = x4[((size_t)b * Cc * HWc + rem) >> 2];
    } else {
        o4[i4] = make_float4(0.f, 0.f, 0.f, 0.f);
    }
}

// ---------------- K6: gather best latter vectors into shift region ---------------
__global__ __launch_bounds__(256) void k_scatter(const _Float16* __restrict__ latH,
                                                 const _Float16* __restrict__ latL,
                                                 const float* __restrict__ nrm,
                                                 const int* __restrict__ bfin,
                                                 const int* __restrict__ pidx,
                                                 const int* __restrict__ qidx,
                                                 float* __restrict__ out) {
    int blk = blockIdx.x;   // 0..31 : 32 masked p each
    int b   = blockIdx.y;
    int tid = threadIdx.x;
    __shared__ float tile[32][257];
    __shared__ int qd[32], pd[32];
    __shared__ float nr[32];
    if (tid < 32) {
        int qc = bfin[b * NP + blk * 32 + tid];
        qd[tid] = qc;
        pd[tid] = pidx[blk * 32 + tid];
        nr[tid] = nrm[b * HWc + qidx[qc]];
    }
    __syncthreads();
    for (int i = tid; i < 32 * 256; i += 256) {
        int pp = i >> 8, c = i & 255;
        size_t o = ((size_t)b * NQ + qd[pp]) * 256 + c;
        tile[pp][c] = ((float)latH[o] + (float)latL[o] * (1.0f / 2048.0f)) * nr[pp];
    }
    __syncthreads();
    float* ob = out + (size_t)b * OUTC * HWc + (size_t)Cc * HWc;
    for (int i = tid; i < 256 * 32; i += 256) {
        int ch = i >> 5, j = i & 31;
        ob[(size_t)ch * HWc + pd[j]] = tile[j][ch];
    }
}

extern "C" void kernel_launch(void* const* d_in, const int* in_sizes, int n_in,
                              void* d_out, int out_size, void* d_ws, size_t ws_size,
                              hipStream_t stream) {
    const float* x    = (const float*)d_in[0];
    const int*   mask = (const int*)d_in[1];
    float* out = (float*)d_out;
    char*  ws  = (char*)d_ws;

    // workspace layout (~33.1 MiB)
    _Float16* latH = (_Float16*)(ws);                    // 12,582,912 B
    _Float16* latL = (_Float16*)(ws + 12582912);         // 12,582,912 B
    _Float16* forH = (_Float16*)(ws + 25165824);         //  4,194,304 B
    _Float16* forL = (_Float16*)(ws + 29360128);         //  4,194,304 B
    float* invn    = (float*)(ws + 33554432);            //    131,072 B
    float* nrm     = (float*)(ws + 33685504);            //    131,072 B
    float* bv1     = (float*)(ws + 33816576);            //    262,144 B
    int*   bi1     = (int*)  (ws + 34078720);            //    262,144 B
    float* bv2     = (float*)(ws + 34340864);            //    262,144 B
    int*   bfin    = (int*)  (ws + 34603008);            //     32,768 B
    int*   pidx    = (int*)  (ws + 34635776);            //      4,096 B
    int*   qidx    = (int*)  (ws + 34639872);            //     12,288 B
    int*   qinv    = (int*)  (ws + 34652160);            //     16,384 B
    int*   cnt     = (int*)  (ws + 34668544);            //         32 B
    int*   fixrows = (int*)  (ws + 34668576);            //      1,024 B

    k_build<<<1, 1024, 0, stream>>>(mask, pidx, qidx, qinv, cnt);
    k_prep<<<640, 256, 0, stream>>>(x, pidx, qinv, latH, latL, forH, forL, invn, nrm);
    k_fill<<<(int)(((size_t)BZc * OUTC * HWc / 4 + 255) / 256), 256, 0, stream>>>(x, out);
    k_gemm<<<dim3(4, QG, BZc), 512, 0, stream>>>(latH, latL, forH, forL, bv1, bi1, bv2);
    k_reduce<<<(BZc * NP + 255) / 256, 256, 0, stream>>>(bv1, bi1, bv2, bfin, cnt, fixrows);
    k_fixup<<<dim3(32, BZc), 256, 0, stream>>>(x, pidx, qidx, invn, cnt, fixrows, bfin);
    k_scatter<<<dim3(32, BZc), 256, 0, stream>>>(latH, latL, nrm, bfin, pidx, qidx, out);
}

// Round 4
// 132.198 us; speedup vs baseline: 3.9792x; 3.9792x over previous
//
#include <hip/hip_runtime.h>
#include <math.h>

#define BZc 8
#define Cc 512
#define C2c 256
#define HWc 4096
#define OUTC 768
#define NP 1024
#define NQ 3072
#define QG 8        // q groups (chunks) for gemm
#define TAU 5e-5f
#define FIXSLOTS 64

typedef _Float16 h8 __attribute__((ext_vector_type(8)));
typedef float f16v __attribute__((ext_vector_type(16)));
typedef float f32x4 __attribute__((ext_vector_type(4)));

// ---------------- K0: build compacted index lists + inverse map + zero counters --
__global__ __launch_bounds__(1024) void k_build(const int* __restrict__ mask,
                                                int* __restrict__ pidx,
                                                int* __restrict__ qidx,
                                                int* __restrict__ qinv,
                                                int* __restrict__ cnt) {
    __shared__ int s0[1024], s1[1024], t0[1024], t1[1024];
    int t = threadIdx.x;
    if (t < 8) cnt[t] = 0;
    int f[4];
    int cp = 0;
#pragma unroll
    for (int j = 0; j < 4; ++j) { f[j] = mask[t * 4 + j]; cp += f[j]; }
    s0[t] = cp; s1[t] = 4 - cp;
    __syncthreads();
    int *a = s0, *b = s1, *c = t0, *d = t1;
    for (int off = 1; off < 1024; off <<= 1) {
        int vp = a[t] + (t >= off ? a[t - off] : 0);
        int vq = b[t] + (t >= off ? b[t - off] : 0);
        c[t] = vp; d[t] = vq;
        __syncthreads();
        int* tmp;
        tmp = a; a = c; c = tmp;
        tmp = b; b = d; d = tmp;
    }
    int ep = a[t] - cp;
    int eq = b[t] - (4 - cp);
#pragma unroll
    for (int j = 0; j < 4; ++j) {
        int idx = t * 4 + j;
        if (f[j]) { pidx[ep] = idx; qinv[idx] = -1; ep++; }
        else      { qidx[eq] = idx; qinv[idx] = eq; eq++; }
    }
}

// ---------------- K1: prep — transpose + fp16 hi/lo split (latter & former) ------
__global__ __launch_bounds__(256) void k_prep(const float* __restrict__ x,
                                              const int* __restrict__ pidx,
                                              const int* __restrict__ qinv,
                                              _Float16* __restrict__ latH,
                                              _Float16* __restrict__ latL,
                                              _Float16* __restrict__ forH,
                                              _Float16* __restrict__ forL,
                                              float* __restrict__ invn,
                                              float* __restrict__ nrm) {
    int id = blockIdx.x;
    bool isLat = id < 512;
    int b  = isLat ? (id >> 6) : ((id - 512) >> 4);
    int bx = isLat ? (id & 63) : ((id - 512) & 15);
    int tid = threadIdx.x;
    __shared__ float tile[64][65];
    __shared__ float sqa[4][64];
    __shared__ float sinv[64];
    __shared__ int rowm[64];
    __shared__ int rowsrc[64];
    if (tid < 64) {
        if (isLat) { int q = bx * 64 + tid; rowsrc[tid] = q; rowm[tid] = qinv[q]; }
        else       { int pc = bx * 64 + tid; rowsrc[tid] = pidx[pc]; rowm[tid] = pc; }
    }
    __syncthreads();
    const float* xb = x + (size_t)b * Cc * HWc + (isLat ? (size_t)C2c * HWc : 0);
    if (isLat) {
        float sacc = 0.f;
        for (int c0 = 0; c0 < 256; c0 += 64) {
            for (int it = 0; it < 16; ++it) {
                int i = tid + it * 256; int cc = i >> 6, qq = i & 63;
                float v = xb[(size_t)(c0 + cc) * HWc + rowsrc[qq]];
                sacc += v * v;
            }
        }
        sqa[tid >> 6][tid & 63] = sacc;
        __syncthreads();
        if (tid < 64) {
            float s = sqa[0][tid] + sqa[1][tid] + sqa[2][tid] + sqa[3][tid];
            float nr = sqrtf(s) + 1e-8f;
            float inv = 1.0f / nr;
            int q = bx * 64 + tid;
            invn[b * HWc + q] = inv; nrm[b * HWc + q] = nr;
            sinv[tid] = inv;
        }
        __syncthreads();
    }
    _Float16* dH = isLat ? latH + (size_t)b * NQ * 256 : forH + (size_t)b * NP * 256;
    _Float16* dL = isLat ? latL + (size_t)b * NQ * 256 : forL + (size_t)b * NP * 256;
    for (int c0 = 0; c0 < 256; c0 += 64) {
        for (int it = 0; it < 16; ++it) {
            int i = tid + it * 256; int cc = i >> 6, qq = i & 63;
            tile[qq][cc] = xb[(size_t)(c0 + cc) * HWc + rowsrc[qq]];
        }
        __syncthreads();
        int qq = tid >> 2, sub = tid & 3;
        int dr = rowm[qq];
        if (dr >= 0) {
            float scale = isLat ? sinv[qq] : 1.0f;
            h8 hv0, hv1, lv0, lv1;
#pragma unroll
            for (int j = 0; j < 8; ++j) {
                float v = tile[qq][sub * 16 + j] * scale;
                _Float16 h = (_Float16)v;
                hv0[j] = h; lv0[j] = (_Float16)((v - (float)h) * 2048.0f);
            }
#pragma unroll
            for (int j = 0; j < 8; ++j) {
                float v = tile[qq][sub * 16 + 8 + j] * scale;
                _Float16 h = (_Float16)v;
                hv1[j] = h; lv1[j] = (_Float16)((v - (float)h) * 2048.0f);
            }
            size_t o = (size_t)dr * 256 + c0 + sub * 16;
            *(h8*)(dH + o) = hv0; *(h8*)(dH + o + 8) = hv1;
            *(h8*)(dL + o) = lv0; *(h8*)(dL + o + 8) = lv1;
        }
        __syncthreads();
    }
}

// ---------------- K2: MFMA fp16x2 GEMM + per-chunk top-2 -------------------------
__global__ __launch_bounds__(512, 2) void k_gemm(const _Float16* __restrict__ latH,
                                                 const _Float16* __restrict__ latL,
                                                 const _Float16* __restrict__ forH,
                                                 const _Float16* __restrict__ forL,
                                                 float* __restrict__ bv1,
                                                 int* __restrict__ bi1,
                                                 float* __restrict__ bv2) {
    int pg = blockIdx.x;
    int qg = blockIdx.y;
    int b  = blockIdx.z;
    int tid = threadIdx.x;
    int w = tid >> 6, lane = tid & 63;
    int l31 = lane & 31, lh = lane >> 5;

    __shared__ __align__(16) _Float16 sH[2][32 * 256];
    __shared__ __align__(16) _Float16 sL[2][32 * 256];

    size_t fo = ((size_t)(b * NP + pg * 256 + w * 32 + l31)) * 256 + lh * 8;
    const _Float16* fH = forH + fo;
    const _Float16* fL = forL + fo;
    h8 BH[16], BL[16];
#pragma unroll
    for (int ks = 0; ks < 16; ++ks) {
        BH[ks] = *(const h8*)(fH + ks * 16);
        BL[ks] = *(const h8*)(fL + ks * 16);
    }

    const _Float16* latHb = latH + (size_t)(b * NQ + qg * 384) * 256;
    const _Float16* latLb = latL + (size_t)(b * NQ + qg * 384) * 256;
    int sq0 = tid >> 5;
    int sq1 = 16 + (tid >> 5);
    int ssl = tid & 31;

    float v1 = -INFINITY, v2 = -INFINITY; int i1 = 0;

    f32x4 rH0, rH1, rL0, rL1;
#define LOADQ(t)                                                                   \
    rH0 = *(const f32x4*)(latHb + ((size_t)((t) * 32 + sq0) * 256 + ssl * 8));     \
    rH1 = *(const f32x4*)(latHb + ((size_t)((t) * 32 + sq1) * 256 + ssl * 8));     \
    rL0 = *(const f32x4*)(latLb + ((size_t)((t) * 32 + sq0) * 256 + ssl * 8));     \
    rL1 = *(const f32x4*)(latLb + ((size_t)((t) * 32 + sq1) * 256 + ssl * 8));
#define WRITEQ(bf)                                                                 \
    *(f32x4*)(&sH[bf][sq0 * 256 + ((ssl ^ sq0) * 8)]) = rH0;                       \
    *(f32x4*)(&sH[bf][sq1 * 256 + ((ssl ^ sq1) * 8)]) = rH1;                       \
    *(f32x4*)(&sL[bf][sq0 * 256 + ((ssl ^ sq0) * 8)]) = rL0;                       \
    *(f32x4*)(&sL[bf][sq1 * 256 + ((ssl ^ sq1) * 8)]) = rL1;

    LOADQ(0); WRITEQ(0);
    __syncthreads();

    for (int t = 0; t < 12; ++t) {
        if (t < 11) { LOADQ(t + 1); }
        const _Float16* bufH = &sH[t & 1][0];
        const _Float16* bufL = &sL[t & 1][0];
        f16v accA = {}, accB = {};
#pragma unroll
        for (int ks = 0; ks < 16; ++ks) {
            int slotA = (ks * 2 + lh) ^ l31;
            h8 aH = *(const h8*)(bufH + l31 * 256 + slotA * 8);
            h8 aL = *(const h8*)(bufL + l31 * 256 + slotA * 8);
            accA = __builtin_amdgcn_mfma_f32_32x32x16_f16(aH, BH[ks], accA, 0, 0, 0);
            accB = __builtin_amdgcn_mfma_f32_32x32x16_f16(aH, BL[ks], accB, 0, 0, 0);
            accB = __builtin_amdgcn_mfma_f32_32x32x16_f16(aL, BH[ks], accB, 0, 0, 0);
        }
        int q0 = qg * 384 + t * 32;
#pragma unroll
        for (int r = 0; r < 16; ++r) {
            float v = accA[r] + accB[r] * (1.0f / 2048.0f);
            int q = q0 + (r & 3) + 8 * (r >> 2) + 4 * lh;
            if (v > v1) { v2 = v1; v1 = v; i1 = q; }
            else if (v > v2) { v2 = v; }
        }
        if (t < 11) { WRITEQ((t + 1) & 1); }
        __syncthreads();
    }
#undef LOADQ
#undef WRITEQ
    float ov1 = __shfl_xor(v1, 32);
    int   oi1 = __shfl_xor(i1, 32);
    float ov2 = __shfl_xor(v2, 32);
    if (ov1 > v1) { v2 = fmaxf(v1, ov2); v1 = ov1; i1 = oi1; }
    else          { v2 = fmaxf(ov1, v2); }
    if (lane < 32) {
        size_t o = ((size_t)b * NP + pg * 256 + w * 32 + lane) * QG + qg;
        bv1[o] = v1; bi1[o] = i1; bv2[o] = v2;
    }
}

// ---------------- K3: merge chunks -> best index + margin flag -------------------
__global__ void k_reduce(const float* __restrict__ bv1, const int* __restrict__ bi1,
                         const float* __restrict__ bv2, int* __restrict__ bfin,
                         int* __restrict__ cnt, int* __restrict__ fixrows) {
    int t = blockIdx.x * blockDim.x + threadIdx.x;
    if (t >= BZc * NP) return;
    float V1 = -INFINITY, V2 = -INFINITY; int I1 = 0;
    for (int c = 0; c < QG; ++c) {
        float a = bv1[(size_t)t * QG + c];
        float a2 = bv2[(size_t)t * QG + c];
        int   i = bi1[(size_t)t * QG + c];
        if (a > V1) { V2 = fmaxf(V1, a2); V1 = a; I1 = i; }
        else        { V2 = fmaxf(V2, a); }
    }
    bfin[t] = I1;
    if (V1 - V2 < TAU) {
        int b = t >> 10;
        int s = atomicAdd(&cnt[b], 1);
        if (s < FIXSLOTS) fixrows[b * FIXSLOTS + s] = t & 1023;
    }
}

// ---------------- K4a: exact fp32 fixup, phase A (per q-quarter partial argmax) --
__global__ __launch_bounds__(256) void k_fixA(const float* __restrict__ x,
                                              const int* __restrict__ pidx,
                                              const int* __restrict__ mask,
                                              const float* __restrict__ invn,
                                              const int* __restrict__ cnt,
                                              const int* __restrict__ fixrows,
                                              float* __restrict__ fixv,
                                              int* __restrict__ fixi) {
    int qg = blockIdx.x, s = blockIdx.y, b = blockIdx.z;
    int n = cnt[b]; if (n > FIXSLOTS) n = FIXSLOTS;
    if (s >= n) return;
    int p = fixrows[b * FIXSLOTS + s];
    int porig = pidx[p];
    int tid = threadIdx.x;
    __shared__ float fs[256];
    fs[tid] = x[((size_t)b * Cc + tid) * HWc + porig];
    __syncthreads();
    const float* lx = x + ((size_t)b * Cc + C2c) * HWc;
    int q0 = qg * 1024 + tid * 4;
    float4 acc = make_float4(0.f, 0.f, 0.f, 0.f);
    for (int c0 = 0; c0 < 256; c0 += 8) {
        float4 v[8];
#pragma unroll
        for (int u = 0; u < 8; ++u)
            v[u] = *(const float4*)(lx + (size_t)(c0 + u) * HWc + q0);
#pragma unroll
        for (int u = 0; u < 8; ++u) {
            float fc = fs[c0 + u];
            acc.x = fmaf(fc, v[u].x, acc.x);
            acc.y = fmaf(fc, v[u].y, acc.y);
            acc.z = fmaf(fc, v[u].z, acc.z);
            acc.w = fmaf(fc, v[u].w, acc.w);
        }
    }
    float vals[4] = {acc.x, acc.y, acc.z, acc.w};
    float bv = -INFINITY; int bq = 1 << 30;
#pragma unroll
    for (int k = 0; k < 4; ++k) {
        int q = q0 + k;
        float val = vals[k] * invn[b * HWc + q];
        if (mask[q] == 0 && val > bv) { bv = val; bq = q; }
    }
    __shared__ float rv[256]; __shared__ int rq[256];
    rv[tid] = bv; rq[tid] = bq; __syncthreads();
    for (int off = 128; off > 0; off >>= 1) {
        if (tid < off) {
            float v2 = rv[tid + off]; int q2 = rq[tid + off];
            if (v2 > rv[tid] || (v2 == rv[tid] && q2 < rq[tid])) { rv[tid] = v2; rq[tid] = q2; }
        }
        __syncthreads();
    }
    if (tid == 0) {
        fixv[(b * FIXSLOTS + s) * 4 + qg] = rv[0];
        fixi[(b * FIXSLOTS + s) * 4 + qg] = rq[0];
    }
}

// ---------------- K4b: fixup phase B — merge quarters, spatial->compact ----------
__global__ void k_fixB(const int* __restrict__ cnt, const int* __restrict__ fixrows,
                       const float* __restrict__ fixv, const int* __restrict__ fixi,
                       const int* __restrict__ qinv, int* __restrict__ bfin) {
    int t = threadIdx.x;                 // 512 threads: b = t>>6, s = t&63
    int b = t >> 6, s = t & 63;
    int n = cnt[b]; if (n > FIXSLOTS) n = FIXSLOTS;
    if (s >= n) return;
    float bv = -INFINITY; int bq = 1 << 30;
    for (int qg = 0; qg < 4; ++qg) {
        float v = fixv[(b * FIXSLOTS + s) * 4 + qg];
        int   q = fixi[(b * FIXSLOTS + s) * 4 + qg];
        if (v > bv || (v == bv && q < bq)) { bv = v; bq = q; }
    }
    int p = fixrows[b * FIXSLOTS + s];
    bfin[b * NP + p] = qinv[bq];
}

// ---------------- K5: out[:, :512] = x ; out[:, 512:] = 0 ------------------------
__global__ __launch_bounds__(256) void k_fill(const float* __restrict__ x,
                                              float* __restrict__ out) {
    size_t i4 = (size_t)blockIdx.x * blockDim.x + threadIdx.x;
    size_t total4 = (size_t)BZc * OUTC * HWc / 4;
    if (i4 >= total4) return;
    size_t e   = i4 * 4;
    size_t per = (size_t)OUTC * HWc;
    size_t b   = e / per;
    size_t rem = e % per;
    int ch = (int)(rem / HWc);
    float4* o4 = (float4*)out;
    if (ch < Cc) {
        const float4* x4 = (const float4*)x;
        o4[i4] = x4[((size_t)b * Cc * HWc + rem) >> 2];
    } else {
        o4[i4] = make_float4(0.f, 0.f, 0.f, 0.f);
    }
}

// ---------------- K6: gather best latter vectors into shift region ---------------
__global__ __launch_bounds__(256) void k_scatter(const _Float16* __restrict__ latH,
                                                 const _Float16* __restrict__ latL,
                                                 const float* __restrict__ nrm,
                                                 const int* __restrict__ bfin,
                                                 const int* __restrict__ pidx,
                                                 const int* __restrict__ qidx,
                                                 float* __restrict__ out) {
    int blk = blockIdx.x;
    int b   = blockIdx.y;
    int tid = threadIdx.x;
    __shared__ float tile[32][257];
    __shared__ int qd[32], pd[32];
    __shared__ float nr[32];
    if (tid < 32) {
        int qc = bfin[b * NP + blk * 32 + tid];
        qd[tid] = qc;
        pd[tid] = pidx[blk * 32 + tid];
        nr[tid] = nrm[b * HWc + qidx[qc]];
    }
    __syncthreads();
    for (int i = tid; i < 32 * 256; i += 256) {
        int pp = i >> 8, c = i & 255;
        size_t o = ((size_t)b * NQ + qd[pp]) * 256 + c;
        tile[pp][c] = ((float)latH[o] + (float)latL[o] * (1.0f / 2048.0f)) * nr[pp];
    }
    __syncthreads();
    float* ob = out + (size_t)b * OUTC * HWc + (size_t)Cc * HWc;
    for (int i = tid; i < 256 * 32; i += 256) {
        int ch = i >> 5, j = i & 31;
        ob[(size_t)ch * HWc + pd[j]] = tile[j][ch];
    }
}

extern "C" void kernel_launch(void* const* d_in, const int* in_sizes, int n_in,
                              void* d_out, int out_size, void* d_ws, size_t ws_size,
                              hipStream_t stream) {
    const float* x    = (const float*)d_in[0];
    const int*   mask = (const int*)d_in[1];
    float* out = (float*)d_out;
    char*  ws  = (char*)d_ws;

    _Float16* latH = (_Float16*)(ws);                    // 12,582,912 B
    _Float16* latL = (_Float16*)(ws + 12582912);         // 12,582,912 B
    _Float16* forH = (_Float16*)(ws + 25165824);         //  4,194,304 B
    _Float16* forL = (_Float16*)(ws + 29360128);         //  4,194,304 B
    float* invn    = (float*)(ws + 33554432);            //    131,072 B
    float* nrm     = (float*)(ws + 33685504);            //    131,072 B
    float* bv1     = (float*)(ws + 33816576);            //    262,144 B
    int*   bi1     = (int*)  (ws + 34078720);            //    262,144 B
    float* bv2     = (float*)(ws + 34340864);            //    262,144 B
    int*   bfin    = (int*)  (ws + 34603008);            //     32,768 B
    int*   pidx    = (int*)  (ws + 34635776);            //      4,096 B
    int*   qidx    = (int*)  (ws + 34639872);            //     12,288 B
    int*   qinv    = (int*)  (ws + 34652160);            //     16,384 B
    int*   cnt     = (int*)  (ws + 34668544);            //         32 B
    int*   fixrows = (int*)  (ws + 34668576);            //      2,048 B (8*64)
    float* fixv    = (float*)(ws + 34670624);            //      8,192 B (8*64*4)
    int*   fixi    = (int*)  (ws + 34678816);            //      8,192 B

    k_build<<<1, 1024, 0, stream>>>(mask, pidx, qidx, qinv, cnt);
    k_prep<<<640, 256, 0, stream>>>(x, pidx, qinv, latH, latL, forH, forL, invn, nrm);
    k_fill<<<(int)(((size_t)BZc * OUTC * HWc / 4 + 255) / 256), 256, 0, stream>>>(x, out);
    k_gemm<<<dim3(4, QG, BZc), 512, 0, stream>>>(latH, latL, forH, forL, bv1, bi1, bv2);
    k_reduce<<<(BZc * NP + 255) / 256, 256, 0, stream>>>(bv1, bi1, bv2, bfin, cnt, fixrows);
    k_fixA<<<dim3(4, FIXSLOTS, BZc), 256, 0, stream>>>(x, pidx, mask, invn, cnt, fixrows, fixv, fixi);
    k_fixB<<<1, 512, 0, stream>>>(cnt, fixrows, fixv, fixi, qinv, bfin);
    k_scatter<<<dim3(32, BZc), 256, 0, stream>>>(latH, latL, nrm, bfin, pidx, qidx, out);
}

// Round 5
// 120.747 us; speedup vs baseline: 4.3565x; 1.0948x over previous
//
#include <hip/hip_runtime.h>
#include <math.h>

#define BZc 8
#define Cc 512
#define C2c 256
#define HWc 4096
#define OUTC 768
#define NP 1024
#define NQ 3072
#define QG 8        // q groups (chunks) for gemm: 384 q each
#define TAU 5e-5f
#define FIXSLOTS 64

typedef _Float16 h8 __attribute__((ext_vector_type(8)));
typedef float f16v __attribute__((ext_vector_type(16)));
typedef float f32x4 __attribute__((ext_vector_type(4)));

// ---------------- K0: compacted index lists + inverse maps + zero counters -------
__global__ __launch_bounds__(1024) void k_build(const int* __restrict__ mask,
                                                int* __restrict__ pidx,
                                                int* __restrict__ qinv,
                                                int* __restrict__ pinv,
                                                int* __restrict__ cnt) {
    __shared__ int s0[1024], s1[1024], t0[1024], t1[1024];
    int t = threadIdx.x;
    if (t < 8) cnt[t] = 0;
    int f[4];
    int cp = 0;
#pragma unroll
    for (int j = 0; j < 4; ++j) { f[j] = mask[t * 4 + j]; cp += f[j]; }
    s0[t] = cp; s1[t] = 4 - cp;
    __syncthreads();
    int *a = s0, *b = s1, *c = t0, *d = t1;
    for (int off = 1; off < 1024; off <<= 1) {
        int vp = a[t] + (t >= off ? a[t - off] : 0);
        int vq = b[t] + (t >= off ? b[t - off] : 0);
        c[t] = vp; d[t] = vq;
        __syncthreads();
        int* tmp;
        tmp = a; a = c; c = tmp;
        tmp = b; b = d; d = tmp;
    }
    int ep = a[t] - cp;
    int eq = b[t] - (4 - cp);
#pragma unroll
    for (int j = 0; j < 4; ++j) {
        int idx = t * 4 + j;
        if (f[j]) { pidx[ep] = idx; pinv[idx] = ep; qinv[idx] = -1; ep++; }
        else      { qinv[idx] = eq; pinv[idx] = -1; eq++; }
    }
}

// ---------------- K1: unified prep — copy/zero out + raw fp16 hi/lo split --------
// blocks 0..511: latter (b=id>>6, 64 spatial cols each) -> out[256:512) copy,
//   latH/latL split rows (unmasked), invn + invnC.
// blocks 512..1023: former -> out[0:256) copy, out[512:768) zeros,
//   forH/forL split rows (masked).
__global__ __launch_bounds__(256) void k_prep(const float* __restrict__ x,
                                              const int* __restrict__ pinv,
                                              const int* __restrict__ qinv,
                                              _Float16* __restrict__ latH,
                                              _Float16* __restrict__ latL,
                                              _Float16* __restrict__ forH,
                                              _Float16* __restrict__ forL,
                                              float* __restrict__ invn,
                                              float* __restrict__ invnC,
                                              float* __restrict__ out) {
    int id = blockIdx.x;
    bool isLat = id < 512;
    int b = isLat ? (id >> 6) : ((id - 512) >> 6);
    int g = isLat ? (id & 63) : ((id - 512) & 63);
    int tid = threadIdx.x;
    __shared__ float tile[64][65];
    __shared__ float sqa[4][64];
    __shared__ int rowm[64];
    if (tid < 64) rowm[tid] = isLat ? qinv[g * 64 + tid] : pinv[g * 64 + tid];
    __syncthreads();
    const float* xb = x + (size_t)b * Cc * HWc + (isLat ? (size_t)C2c * HWc : 0);
    float* ob = out + (size_t)b * OUTC * HWc + (isLat ? (size_t)C2c * HWc : 0);
    _Float16* dH = isLat ? latH + (size_t)b * NQ * 256 : forH + (size_t)b * NP * 256;
    _Float16* dL = isLat ? latL + (size_t)b * NQ * 256 : forL + (size_t)b * NP * 256;
    float sacc = 0.f;
    for (int c0 = 0; c0 < 256; c0 += 64) {
        for (int it = 0; it < 16; ++it) {
            int i = tid + it * 256; int cc = i >> 6, qq = i & 63;
            float v = xb[(size_t)(c0 + cc) * HWc + g * 64 + qq];
            tile[qq][cc] = v;
            ob[(size_t)(c0 + cc) * HWc + g * 64 + qq] = v;   // out copy
            sacc += v * v;                                    // qq fixed per thread
        }
        __syncthreads();
        int qq = tid >> 2, sub = tid & 3;
        int dr = rowm[qq];
        if (dr >= 0) {
            h8 hv0, hv1, lv0, lv1;
#pragma unroll
            for (int j = 0; j < 8; ++j) {
                float v = tile[qq][sub * 16 + j];
                _Float16 h = (_Float16)v;
                hv0[j] = h; lv0[j] = (_Float16)((v - (float)h) * 2048.0f);
            }
#pragma unroll
            for (int j = 0; j < 8; ++j) {
                float v = tile[qq][sub * 16 + 8 + j];
                _Float16 h = (_Float16)v;
                hv1[j] = h; lv1[j] = (_Float16)((v - (float)h) * 2048.0f);
            }
            size_t o = (size_t)dr * 256 + c0 + sub * 16;
            *(h8*)(dH + o) = hv0; *(h8*)(dH + o + 8) = hv1;
            *(h8*)(dL + o) = lv0; *(h8*)(dL + o + 8) = lv1;
        }
        __syncthreads();
    }
    if (isLat) {
        sqa[tid >> 6][tid & 63] = sacc;
        __syncthreads();
        if (tid < 64) {
            float s = sqa[0][tid] + sqa[1][tid] + sqa[2][tid] + sqa[3][tid];
            float inv = 1.0f / (sqrtf(s) + 1e-8f);
            int q = g * 64 + tid;
            invn[b * HWc + q] = inv;
            int qc = rowm[tid];
            if (qc >= 0) invnC[b * NQ + qc] = inv;
        }
    } else {
        // zero the shift region for my 64 columns (scatter overwrites masked later)
        float4 z = make_float4(0.f, 0.f, 0.f, 0.f);
        float* sb = out + (size_t)b * OUTC * HWc + (size_t)Cc * HWc;
        for (int i = tid; i < 256 * 16; i += 256) {
            int ch = i >> 4, j4 = i & 15;
            *(float4*)(sb + (size_t)ch * HWc + g * 64 + j4 * 4) = z;
        }
    }
}

// ---------------- K2: MFMA fp16x2 GEMM (raw) + invn epilogue + per-chunk top-2 ---
__global__ __launch_bounds__(512, 2) void k_gemm(const _Float16* __restrict__ latH,
                                                 const _Float16* __restrict__ latL,
                                                 const _Float16* __restrict__ forH,
                                                 const _Float16* __restrict__ forL,
                                                 const float* __restrict__ invnC,
                                                 float* __restrict__ bv1,
                                                 int* __restrict__ bi1,
                                                 float* __restrict__ bv2) {
    int pg = blockIdx.x;
    int qg = blockIdx.y;
    int b  = blockIdx.z;
    int tid = threadIdx.x;
    int w = tid >> 6, lane = tid & 63;
    int l31 = lane & 31, lh = lane >> 5;

    __shared__ __align__(16) _Float16 sH[2][32 * 256];
    __shared__ __align__(16) _Float16 sL[2][32 * 256];
    __shared__ float sInv[384];

    if (tid < 384) sInv[tid] = invnC[b * NQ + qg * 384 + tid];

    size_t fo = ((size_t)(b * NP + pg * 256 + w * 32 + l31)) * 256 + lh * 8;
    const _Float16* fH = forH + fo;
    const _Float16* fL = forL + fo;
    h8 BH[16], BL[16];
#pragma unroll
    for (int ks = 0; ks < 16; ++ks) {
        BH[ks] = *(const h8*)(fH + ks * 16);
        BL[ks] = *(const h8*)(fL + ks * 16);
    }

    const _Float16* latHb = latH + (size_t)(b * NQ + qg * 384) * 256;
    const _Float16* latLb = latL + (size_t)(b * NQ + qg * 384) * 256;
    int sq0 = tid >> 5;
    int sq1 = 16 + (tid >> 5);
    int ssl = tid & 31;

    float v1 = -INFINITY, v2 = -INFINITY; int i1 = 0;

    f32x4 rH0, rH1, rL0, rL1;
#define LOADQ(t)                                                                   \
    rH0 = *(const f32x4*)(latHb + ((size_t)((t) * 32 + sq0) * 256 + ssl * 8));     \
    rH1 = *(const f32x4*)(latHb + ((size_t)((t) * 32 + sq1) * 256 + ssl * 8));     \
    rL0 = *(const f32x4*)(latLb + ((size_t)((t) * 32 + sq0) * 256 + ssl * 8));     \
    rL1 = *(const f32x4*)(latLb + ((size_t)((t) * 32 + sq1) * 256 + ssl * 8));
#define WRITEQ(bf)                                                                 \
    *(f32x4*)(&sH[bf][sq0 * 256 + ((ssl ^ sq0) * 8)]) = rH0;                       \
    *(f32x4*)(&sH[bf][sq1 * 256 + ((ssl ^ sq1) * 8)]) = rH1;                       \
    *(f32x4*)(&sL[bf][sq0 * 256 + ((ssl ^ sq0) * 8)]) = rL0;                       \
    *(f32x4*)(&sL[bf][sq1 * 256 + ((ssl ^ sq1) * 8)]) = rL1;

    LOADQ(0); WRITEQ(0);
    __syncthreads();

    for (int t = 0; t < 12; ++t) {
        if (t < 11) { LOADQ(t + 1); }
        const _Float16* bufH = &sH[t & 1][0];
        const _Float16* bufL = &sL[t & 1][0];
        f16v accA = {}, accB = {};
#pragma unroll
        for (int ks = 0; ks < 16; ++ks) {
            int slotA = (ks * 2 + lh) ^ l31;
            h8 aH = *(const h8*)(bufH + l31 * 256 + slotA * 8);
            h8 aL = *(const h8*)(bufL + l31 * 256 + slotA * 8);
            accA = __builtin_amdgcn_mfma_f32_32x32x16_f16(aH, BH[ks], accA, 0, 0, 0);
            accB = __builtin_amdgcn_mfma_f32_32x32x16_f16(aH, BL[ks], accB, 0, 0, 0);
            accB = __builtin_amdgcn_mfma_f32_32x32x16_f16(aL, BH[ks], accB, 0, 0, 0);
        }
#pragma unroll
        for (int r = 0; r < 16; ++r) {
            int off = (r & 3) + 8 * (r >> 2) + 4 * lh;
            float v = (accA[r] + accB[r] * (1.0f / 2048.0f)) * sInv[t * 32 + off];
            int q = qg * 384 + t * 32 + off;
            if (v > v1) { v2 = v1; v1 = v; i1 = q; }
            else if (v > v2) { v2 = v; }
        }
        if (t < 11) { WRITEQ((t + 1) & 1); }
        __syncthreads();
    }
#undef LOADQ
#undef WRITEQ
    float ov1 = __shfl_xor(v1, 32);
    int   oi1 = __shfl_xor(i1, 32);
    float ov2 = __shfl_xor(v2, 32);
    if (ov1 > v1) { v2 = fmaxf(v1, ov2); v1 = ov1; i1 = oi1; }
    else          { v2 = fmaxf(ov1, v2); }
    if (lane < 32) {
        size_t o = ((size_t)b * NP + pg * 256 + w * 32 + lane) * QG + qg;
        bv1[o] = v1; bi1[o] = i1; bv2[o] = v2;
    }
}

// ---------------- K3: merge chunks -> best index + margin flag -------------------
__global__ void k_reduce(const float* __restrict__ bv1, const int* __restrict__ bi1,
                         const float* __restrict__ bv2, int* __restrict__ bfin,
                         int* __restrict__ cnt, int* __restrict__ fixrows) {
    int t = blockIdx.x * blockDim.x + threadIdx.x;
    if (t >= BZc * NP) return;
    float V1 = -INFINITY, V2 = -INFINITY; int I1 = 0;
    for (int c = 0; c < QG; ++c) {
        float a = bv1[(size_t)t * QG + c];
        float a2 = bv2[(size_t)t * QG + c];
        int   i = bi1[(size_t)t * QG + c];
        if (a > V1) { V2 = fmaxf(V1, a2); V1 = a; I1 = i; }
        else        { V2 = fmaxf(V2, a); }
    }
    bfin[t] = I1;
    if (V1 - V2 < TAU) {
        int b = t >> 10;
        int s = atomicAdd(&cnt[b], 1);
        if (s < FIXSLOTS) fixrows[b * FIXSLOTS + s] = t & 1023;
    }
}

// ---------------- K4a: exact fp32 fixup, phase A (per q-quarter partial argmax) --
__global__ __launch_bounds__(256) void k_fixA(const float* __restrict__ x,
                                              const int* __restrict__ pidx,
                                              const int* __restrict__ mask,
                                              const float* __restrict__ invn,
                                              const int* __restrict__ cnt,
                                              const int* __restrict__ fixrows,
                                              float* __restrict__ fixv,
                                              int* __restrict__ fixi) {
    int qg = blockIdx.x, s = blockIdx.y, b = blockIdx.z;
    int n = cnt[b]; if (n > FIXSLOTS) n = FIXSLOTS;
    if (s >= n) return;
    int p = fixrows[b * FIXSLOTS + s];
    int porig = pidx[p];
    int tid = threadIdx.x;
    __shared__ float fs[256];
    fs[tid] = x[((size_t)b * Cc + tid) * HWc + porig];
    __syncthreads();
    const float* lx = x + ((size_t)b * Cc + C2c) * HWc;
    int q0 = qg * 1024 + tid * 4;
    float4 acc = make_float4(0.f, 0.f, 0.f, 0.f);
    for (int c0 = 0; c0 < 256; c0 += 8) {
        float4 v[8];
#pragma unroll
        for (int u = 0; u < 8; ++u)
            v[u] = *(const float4*)(lx + (size_t)(c0 + u) * HWc + q0);
#pragma unroll
        for (int u = 0; u < 8; ++u) {
            float fc = fs[c0 + u];
            acc.x = fmaf(fc, v[u].x, acc.x);
            acc.y = fmaf(fc, v[u].y, acc.y);
            acc.z = fmaf(fc, v[u].z, acc.z);
            acc.w = fmaf(fc, v[u].w, acc.w);
        }
    }
    float vals[4] = {acc.x, acc.y, acc.z, acc.w};
    float bv = -INFINITY; int bq = 1 << 30;
#pragma unroll
    for (int k = 0; k < 4; ++k) {
        int q = q0 + k;
        float val = vals[k] * invn[b * HWc + q];
        if (mask[q] == 0 && val > bv) { bv = val; bq = q; }
    }
    __shared__ float rv[256]; __shared__ int rq[256];
    rv[tid] = bv; rq[tid] = bq; __syncthreads();
    for (int off = 128; off > 0; off >>= 1) {
        if (tid < off) {
            float v2 = rv[tid + off]; int q2 = rq[tid + off];
            if (v2 > rv[tid] || (v2 == rv[tid] && q2 < rq[tid])) { rv[tid] = v2; rq[tid] = q2; }
        }
        __syncthreads();
    }
    if (tid == 0) {
        fixv[(b * FIXSLOTS + s) * 4 + qg] = rv[0];
        fixi[(b * FIXSLOTS + s) * 4 + qg] = rq[0];
    }
}

// ---------------- K4b: fixup phase B — merge quarters, spatial->compact ----------
__global__ void k_fixB(const int* __restrict__ cnt, const int* __restrict__ fixrows,
                       const float* __restrict__ fixv, const int* __restrict__ fixi,
                       const int* __restrict__ qinv, int* __restrict__ bfin) {
    int t = threadIdx.x;                 // 512 threads: b = t>>6, s = t&63
    int b = t >> 6, s = t & 63;
    int n = cnt[b]; if (n > FIXSLOTS) n = FIXSLOTS;
    if (s >= n) return;
    float bv = -INFINITY; int bq = 1 << 30;
    for (int qg = 0; qg < 4; ++qg) {
        float v = fixv[(b * FIXSLOTS + s) * 4 + qg];
        int   q = fixi[(b * FIXSLOTS + s) * 4 + qg];
        if (v > bv || (v == bv && q < bq)) { bv = v; bq = q; }
    }
    int p = fixrows[b * FIXSLOTS + s];
    bfin[b * NP + p] = qinv[bq];
}

// ---------------- K5: gather best latter vectors into shift region ---------------
__global__ __launch_bounds__(256) void k_scatter(const _Float16* __restrict__ latH,
                                                 const _Float16* __restrict__ latL,
                                                 const int* __restrict__ bfin,
                                                 const int* __restrict__ pidx,
                                                 float* __restrict__ out) {
    int blk = blockIdx.x;
    int b   = blockIdx.y;
    int tid = threadIdx.x;
    __shared__ float tile[32][257];
    __shared__ int qd[32], pd[32];
    if (tid < 32) {
        qd[tid] = bfin[b * NP + blk * 32 + tid];
        pd[tid] = pidx[blk * 32 + tid];
    }
    __syncthreads();
    for (int i = tid; i < 32 * 256; i += 256) {
        int pp = i >> 8, c = i & 255;
        size_t o = ((size_t)b * NQ + qd[pp]) * 256 + c;
        tile[pp][c] = (float)latH[o] + (float)latL[o] * (1.0f / 2048.0f);
    }
    __syncthreads();
    float* ob = out + (size_t)b * OUTC * HWc + (size_t)Cc * HWc;
    for (int i = tid; i < 256 * 32; i += 256) {
        int ch = i >> 5, j = i & 31;
        ob[(size_t)ch * HWc + pd[j]] = tile[j][ch];
    }
}

extern "C" void kernel_launch(void* const* d_in, const int* in_sizes, int n_in,
                              void* d_out, int out_size, void* d_ws, size_t ws_size,
                              hipStream_t stream) {
    const float* x    = (const float*)d_in[0];
    const int*   mask = (const int*)d_in[1];
    float* out = (float*)d_out;
    char*  ws  = (char*)d_ws;

    _Float16* latH = (_Float16*)(ws);                    // 12,582,912 B
    _Float16* latL = (_Float16*)(ws + 12582912);         // 12,582,912 B
    _Float16* forH = (_Float16*)(ws + 25165824);         //  4,194,304 B
    _Float16* forL = (_Float16*)(ws + 29360128);         //  4,194,304 B
    float* invn    = (float*)(ws + 33554432);            //    131,072 B
    float* invnC   = (float*)(ws + 33685504);            //     98,304 B
    float* bv1     = (float*)(ws + 33783808);            //    262,144 B
    int*   bi1     = (int*)  (ws + 34045952);            //    262,144 B
    float* bv2     = (float*)(ws + 34308096);            //    262,144 B
    int*   bfin    = (int*)  (ws + 34570240);            //     32,768 B
    int*   pidx    = (int*)  (ws + 34603008);            //      4,096 B
    int*   qinv    = (int*)  (ws + 34607104);            //     16,384 B
    int*   pinv    = (int*)  (ws + 34623488);            //     16,384 B
    int*   cnt     = (int*)  (ws + 34639872);            //         32 B
    int*   fixrows = (int*)  (ws + 34639904);            //      2,048 B
    float* fixv    = (float*)(ws + 34641952);            //      8,192 B
    int*   fixi    = (int*)  (ws + 34650144);            //      8,192 B

    k_build<<<1, 1024, 0, stream>>>(mask, pidx, qinv, pinv, cnt);
    k_prep<<<1024, 256, 0, stream>>>(x, pinv, qinv, latH, latL, forH, forL, invn, invnC, out);
    k_gemm<<<dim3(4, QG, BZc), 512, 0, stream>>>(latH, latL, forH, forL, invnC, bv1, bi1, bv2);
    k_reduce<<<(BZc * NP + 255) / 256, 256, 0, stream>>>(bv1, bi1, bv2, bfin, cnt, fixrows);
    k_fixA<<<dim3(4, FIXSLOTS, BZc), 256, 0, stream>>>(x, pidx, mask, invn, cnt, fixrows, fixv, fixi);
    k_fixB<<<1, 512, 0, stream>>>(cnt, fixrows, fixv, fixi, qinv, bfin);
    k_scatter<<<dim3(32, BZc), 256, 0, stream>>>(latH, latL, bfin, pidx, out);
}

// Round 7
// 113.193 us; speedup vs baseline: 4.6473x; 1.0667x over previous
//
#include <hip/hip_runtime.h>
#include <math.h>

#define BZc 8
#define Cc 512
#define C2c 256
#define HWc 4096
#define OUTC 768
#define NP 1024
#define NQ 3072
#define QG 8        // q groups (chunks) for gemm: 384 q each
#define TAU 5e-5f
#define FIXSLOTS 64

typedef _Float16 h8 __attribute__((ext_vector_type(8)));
typedef float f16v __attribute__((ext_vector_type(16)));
typedef float f32x4 __attribute__((ext_vector_type(4)));

// ---------------- K0: compacted index lists + inverse maps + zero counters -------
__global__ __launch_bounds__(1024) void k_build(const int* __restrict__ mask,
                                                int* __restrict__ pidx,
                                                int* __restrict__ qinv,
                                                int* __restrict__ pinv,
                                                int* __restrict__ cnt) {
    __shared__ int s0[1024], s1[1024], t0[1024], t1[1024];
    int t = threadIdx.x;
    if (t < 8) cnt[t] = 0;
    int f[4];
    int cp = 0;
#pragma unroll
    for (int j = 0; j < 4; ++j) { f[j] = mask[t * 4 + j]; cp += f[j]; }
    s0[t] = cp; s1[t] = 4 - cp;
    __syncthreads();
    int *a = s0, *b = s1, *c = t0, *d = t1;
    for (int off = 1; off < 1024; off <<= 1) {
        int vp = a[t] + (t >= off ? a[t - off] : 0);
        int vq = b[t] + (t >= off ? b[t - off] : 0);
        c[t] = vp; d[t] = vq;
        __syncthreads();
        int* tmp;
        tmp = a; a = c; c = tmp;
        tmp = b; b = d; d = tmp;
    }
    int ep = a[t] - cp;
    int eq = b[t] - (4 - cp);
#pragma unroll
    for (int j = 0; j < 4; ++j) {
        int idx = t * 4 + j;
        if (f[j]) { pidx[ep] = idx; pinv[idx] = ep; qinv[idx] = -1; ep++; }
        else      { qinv[idx] = eq; pinv[idx] = -1; eq++; }
    }
}

// ---------------- K1: unified prep — float4 copy/zero + raw fp16 hi/lo split -----
// blocks 0..511: latter (b=id>>6, 64 spatial cols each) -> out[256:512) copy,
//   latH/latL split rows (unmasked), invn + invnC.
// blocks 512..1023: former -> out[0:256) copy, out[512:768) zeros,
//   forH/forL split rows (masked).
__global__ __launch_bounds__(256) void k_prep(const float* __restrict__ x,
                                              const int* __restrict__ pinv,
                                              const int* __restrict__ qinv,
                                              _Float16* __restrict__ latH,
                                              _Float16* __restrict__ latL,
                                              _Float16* __restrict__ forH,
                                              _Float16* __restrict__ forL,
                                              float* __restrict__ invn,
                                              float* __restrict__ invnC,
                                              float* __restrict__ out) {
    int id = blockIdx.x;
    bool isLat = id < 512;
    int b = isLat ? (id >> 6) : ((id - 512) >> 6);
    int g = isLat ? (id & 63) : ((id - 512) & 63);
    int tid = threadIdx.x;
    __shared__ float tile[64][65];   // [local ch][col], 65: bank stride 1 mod 32
    __shared__ float ssq[16][65];
    __shared__ int rowm[64];
    if (tid < 64) rowm[tid] = isLat ? qinv[g * 64 + tid] : pinv[g * 64 + tid];
    __syncthreads();
    const float* xb = x + (size_t)b * Cc * HWc + (isLat ? (size_t)C2c * HWc : 0);
    float* ob = out + (size_t)b * OUTC * HWc + (isLat ? (size_t)C2c * HWc : 0);
    _Float16* dH = isLat ? latH + (size_t)b * NQ * 256 : forH + (size_t)b * NP * 256;
    _Float16* dL = isLat ? latL + (size_t)b * NQ * 256 : forL + (size_t)b * NP * 256;

    int cr = tid >> 4;           // 0..15: channel row within a 16-ch group
    int c4 = (tid & 15) * 4;     // column quad
    float s0 = 0.f, s1 = 0.f, s2 = 0.f, s3 = 0.f;

    for (int c0 = 0; c0 < 256; c0 += 64) {
        // stage 64ch x 64col chunk: float4 load + float4 nontemporal copy + LDS
#pragma unroll
        for (int p = 0; p < 4; ++p) {
            int lch = p * 16 + cr;
            int ch = c0 + lch;
            const f32x4 v = *(const f32x4*)(xb + (size_t)ch * HWc + g * 64 + c4);
            __builtin_nontemporal_store(v, (f32x4*)(ob + (size_t)ch * HWc + g * 64 + c4));
            if (isLat) {
                s0 = fmaf(v.x, v.x, s0); s1 = fmaf(v.y, v.y, s1);
                s2 = fmaf(v.z, v.z, s2); s3 = fmaf(v.w, v.w, s3);
            }
            tile[lch][c4]     = v.x;
            tile[lch][c4 + 1] = v.y;
            tile[lch][c4 + 2] = v.z;
            tile[lch][c4 + 3] = v.w;
        }
        __syncthreads();
        // split: thread (qq, sub) emits 16 ch (h8 hi/lo pair) for column qq
        int qq = tid >> 2, sub = tid & 3;
        int dr = rowm[qq];
        if (dr >= 0) {
            h8 hv0, hv1, lv0, lv1;
#pragma unroll
            for (int j = 0; j < 8; ++j) {
                float v = tile[sub * 16 + j][qq];
                _Float16 h = (_Float16)v;
                hv0[j] = h; lv0[j] = (_Float16)((v - (float)h) * 2048.0f);
            }
#pragma unroll
            for (int j = 0; j < 8; ++j) {
                float v = tile[sub * 16 + 8 + j][qq];
                _Float16 h = (_Float16)v;
                hv1[j] = h; lv1[j] = (_Float16)((v - (float)h) * 2048.0f);
            }
            size_t o = (size_t)dr * 256 + c0 + sub * 16;
            *(h8*)(dH + o) = hv0; *(h8*)(dH + o + 8) = hv1;
            *(h8*)(dL + o) = lv0; *(h8*)(dL + o + 8) = lv1;
        }
        __syncthreads();
    }
    if (isLat) {
        ssq[cr][c4] = s0; ssq[cr][c4 + 1] = s1; ssq[cr][c4 + 2] = s2; ssq[cr][c4 + 3] = s3;
        __syncthreads();
        if (tid < 64) {
            float s = 0.f;
#pragma unroll
            for (int r = 0; r < 16; ++r) s += ssq[r][tid];
            float inv = 1.0f / (sqrtf(s) + 1e-8f);
            int q = g * 64 + tid;
            invn[b * HWc + q] = inv;
            int qc = rowm[tid];
            if (qc >= 0) invnC[b * NQ + qc] = inv;
        }
    } else {
        // zero the shift region for my 64 columns (scatter overwrites masked later)
        f32x4 z = {0.f, 0.f, 0.f, 0.f};
        float* sb = out + (size_t)b * OUTC * HWc + (size_t)Cc * HWc;
        for (int i = tid; i < 256 * 16; i += 256) {
            int ch = i >> 4, j4 = i & 15;
            __builtin_nontemporal_store(z, (f32x4*)(sb + (size_t)ch * HWc + g * 64 + j4 * 4));
        }
    }
}

// ---------------- K2: MFMA fp16x2 GEMM (raw) + invn epilogue + per-chunk top-2 ---
__global__ __launch_bounds__(512, 2) void k_gemm(const _Float16* __restrict__ latH,
                                                 const _Float16* __restrict__ latL,
                                                 const _Float16* __restrict__ forH,
                                                 const _Float16* __restrict__ forL,
                                                 const float* __restrict__ invnC,
                                                 float* __restrict__ bv1,
                                                 int* __restrict__ bi1,
                                                 float* __restrict__ bv2) {
    int pg = blockIdx.x;
    int qg = blockIdx.y;
    int b  = blockIdx.z;
    int tid = threadIdx.x;
    int w = tid >> 6, lane = tid & 63;
    int l31 = lane & 31, lh = lane >> 5;

    __shared__ __align__(16) _Float16 sH[2][32 * 256];
    __shared__ __align__(16) _Float16 sL[2][32 * 256];
    __shared__ float sInv[384];

    if (tid < 384) sInv[tid] = invnC[b * NQ + qg * 384 + tid];

    size_t fo = ((size_t)(b * NP + pg * 256 + w * 32 + l31)) * 256 + lh * 8;
    const _Float16* fH = forH + fo;
    const _Float16* fL = forL + fo;
    h8 BH[16], BL[16];
#pragma unroll
    for (int ks = 0; ks < 16; ++ks) {
        BH[ks] = *(const h8*)(fH + ks * 16);
        BL[ks] = *(const h8*)(fL + ks * 16);
    }

    const _Float16* latHb = latH + (size_t)(b * NQ + qg * 384) * 256;
    const _Float16* latLb = latL + (size_t)(b * NQ + qg * 384) * 256;
    int sq0 = tid >> 5;
    int sq1 = 16 + (tid >> 5);
    int ssl = tid & 31;

    float v1 = -INFINITY, v2 = -INFINITY; int i1 = 0;

    f32x4 rH0, rH1, rL0, rL1;
#define LOADQ(t)                                                                   \
    rH0 = *(const f32x4*)(latHb + ((size_t)((t) * 32 + sq0) * 256 + ssl * 8));     \
    rH1 = *(const f32x4*)(latHb + ((size_t)((t) * 32 + sq1) * 256 + ssl * 8));     \
    rL0 = *(const f32x4*)(latLb + ((size_t)((t) * 32 + sq0) * 256 + ssl * 8));     \
    rL1 = *(const f32x4*)(latLb + ((size_t)((t) * 32 + sq1) * 256 + ssl * 8));
#define WRITEQ(bf)                                                                 \
    *(f32x4*)(&sH[bf][sq0 * 256 + ((ssl ^ sq0) * 8)]) = rH0;                       \
    *(f32x4*)(&sH[bf][sq1 * 256 + ((ssl ^ sq1) * 8)]) = rH1;                       \
    *(f32x4*)(&sL[bf][sq0 * 256 + ((ssl ^ sq0) * 8)]) = rL0;                       \
    *(f32x4*)(&sL[bf][sq1 * 256 + ((ssl ^ sq1) * 8)]) = rL1;

    LOADQ(0); WRITEQ(0);
    __syncthreads();

    for (int t = 0; t < 12; ++t) {
        if (t < 11) { LOADQ(t + 1); }
        const _Float16* bufH = &sH[t & 1][0];
        const _Float16* bufL = &sL[t & 1][0];
        f16v accA = {}, accB = {};
#pragma unroll
        for (int ks = 0; ks < 16; ++ks) {
            int slotA = (ks * 2 + lh) ^ l31;
            h8 aH = *(const h8*)(bufH + l31 * 256 + slotA * 8);
            h8 aL = *(const h8*)(bufL + l31 * 256 + slotA * 8);
            accA = __builtin_amdgcn_mfma_f32_32x32x16_f16(aH, BH[ks], accA, 0, 0, 0);
            accB = __builtin_amdgcn_mfma_f32_32x32x16_f16(aH, BL[ks], accB, 0, 0, 0);
            accB = __builtin_amdgcn_mfma_f32_32x32x16_f16(aL, BH[ks], accB, 0, 0, 0);
        }
#pragma unroll
        for (int r = 0; r < 16; ++r) {
            int off = (r & 3) + 8 * (r >> 2) + 4 * lh;
            float v = (accA[r] + accB[r] * (1.0f / 2048.0f)) * sInv[t * 32 + off];
            int q = qg * 384 + t * 32 + off;
            if (v > v1) { v2 = v1; v1 = v; i1 = q; }
            else if (v > v2) { v2 = v; }
        }
        if (t < 11) { WRITEQ((t + 1) & 1); }
        __syncthreads();
    }
#undef LOADQ
#undef WRITEQ
    float ov1 = __shfl_xor(v1, 32);
    int   oi1 = __shfl_xor(i1, 32);
    float ov2 = __shfl_xor(v2, 32);
    if (ov1 > v1) { v2 = fmaxf(v1, ov2); v1 = ov1; i1 = oi1; }
    else          { v2 = fmaxf(ov1, v2); }
    if (lane < 32) {
        size_t o = ((size_t)b * NP + pg * 256 + w * 32 + lane) * QG + qg;
        bv1[o] = v1; bi1[o] = i1; bv2[o] = v2;
    }
}

// ---------------- K3: merge chunks -> best index + margin flag -------------------
__global__ void k_reduce(const float* __restrict__ bv1, const int* __restrict__ bi1,
                         const float* __restrict__ bv2, int* __restrict__ bfin,
                         int* __restrict__ cnt, int* __restrict__ fixrows) {
    int t = blockIdx.x * blockDim.x + threadIdx.x;
    if (t >= BZc * NP) return;
    float V1 = -INFINITY, V2 = -INFINITY; int I1 = 0;
    for (int c = 0; c < QG; ++c) {
        float a = bv1[(size_t)t * QG + c];
        float a2 = bv2[(size_t)t * QG + c];
        int   i = bi1[(size_t)t * QG + c];
        if (a > V1) { V2 = fmaxf(V1, a2); V1 = a; I1 = i; }
        else        { V2 = fmaxf(V2, a); }
    }
    bfin[t] = I1;
    if (V1 - V2 < TAU) {
        int b = t >> 10;
        int s = atomicAdd(&cnt[b], 1);
        if (s < FIXSLOTS) fixrows[b * FIXSLOTS + s] = t & 1023;
    }
}

// ---------------- K4a: exact fp32 fixup, phase A (per q-quarter partial argmax) --
__global__ __launch_bounds__(256) void k_fixA(const float* __restrict__ x,
                                              const int* __restrict__ pidx,
                                              const int* __restrict__ mask,
                                              const float* __restrict__ invn,
                                              const int* __restrict__ cnt,
                                              const int* __restrict__ fixrows,
                                              float* __restrict__ fixv,
                                              int* __restrict__ fixi) {
    int qg = blockIdx.x, s = blockIdx.y, b = blockIdx.z;
    int n = cnt[b]; if (n > FIXSLOTS) n = FIXSLOTS;
    if (s >= n) return;
    int p = fixrows[b * FIXSLOTS + s];
    int porig = pidx[p];
    int tid = threadIdx.x;
    __shared__ float fs[256];
    fs[tid] = x[((size_t)b * Cc + tid) * HWc + porig];
    __syncthreads();
    const float* lx = x + ((size_t)b * Cc + C2c) * HWc;
    int q0 = qg * 1024 + tid * 4;
    float4 acc = make_float4(0.f, 0.f, 0.f, 0.f);
    for (int c0 = 0; c0 < 256; c0 += 8) {
        float4 v[8];
#pragma unroll
        for (int u = 0; u < 8; ++u)
            v[u] = *(const float4*)(lx + (size_t)(c0 + u) * HWc + q0);
#pragma unroll
        for (int u = 0; u < 8; ++u) {
            float fc = fs[c0 + u];
            acc.x = fmaf(fc, v[u].x, acc.x);
            acc.y = fmaf(fc, v[u].y, acc.y);
            acc.z = fmaf(fc, v[u].z, acc.z);
            acc.w = fmaf(fc, v[u].w, acc.w);
        }
    }
    float vals[4] = {acc.x, acc.y, acc.z, acc.w};
    float bv = -INFINITY; int bq = 1 << 30;
#pragma unroll
    for (int k = 0; k < 4; ++k) {
        int q = q0 + k;
        float val = vals[k] * invn[b * HWc + q];
        if (mask[q] == 0 && val > bv) { bv = val; bq = q; }
    }
    __shared__ float rv[256]; __shared__ int rq[256];
    rv[tid] = bv; rq[tid] = bq; __syncthreads();
    for (int off = 128; off > 0; off >>= 1) {
        if (tid < off) {
            float v2 = rv[tid + off]; int q2 = rq[tid + off];
            if (v2 > rv[tid] || (v2 == rv[tid] && q2 < rq[tid])) { rv[tid] = v2; rq[tid] = q2; }
        }
        __syncthreads();
    }
    if (tid == 0) {
        fixv[(b * FIXSLOTS + s) * 4 + qg] = rv[0];
        fixi[(b * FIXSLOTS + s) * 4 + qg] = rq[0];
    }
}

// ---------------- K4b: fixup phase B — merge quarters, spatial->compact ----------
__global__ void k_fixB(const int* __restrict__ cnt, const int* __restrict__ fixrows,
                       const float* __restrict__ fixv, const int* __restrict__ fixi,
                       const int* __restrict__ qinv, int* __restrict__ bfin) {
    int t = threadIdx.x;                 // 512 threads: b = t>>6, s = t&63
    int b = t >> 6, s = t & 63;
    int n = cnt[b]; if (n > FIXSLOTS) n = FIXSLOTS;
    if (s >= n) return;
    float bv = -INFINITY; int bq = 1 << 30;
    for (int qg = 0; qg < 4; ++qg) {
        float v = fixv[(b * FIXSLOTS + s) * 4 + qg];
        int   q = fixi[(b * FIXSLOTS + s) * 4 + qg];
        if (v > bv || (v == bv && q < bq)) { bv = v; bq = q; }
    }
    int p = fixrows[b * FIXSLOTS + s];
    bfin[b * NP + p] = qinv[bq];
}

// ---------------- K5: gather best latter vectors into shift region ---------------
__global__ __launch_bounds__(256) void k_scatter(const _Float16* __restrict__ latH,
                                                 const _Float16* __restrict__ latL,
                                                 const int* __restrict__ bfin,
                                                 const int* __restrict__ pidx,
                                                 float* __restrict__ out) {
    int blk = blockIdx.x;
    int b   = blockIdx.y;
    int tid = threadIdx.x;
    __shared__ float tile[32][257];
    __shared__ int qd[32], pd[32];
    if (tid < 32) {
        qd[tid] = bfin[b * NP + blk * 32 + tid];
        pd[tid] = pidx[blk * 32 + tid];
    }
    __syncthreads();
    for (int i = tid; i < 32 * 256; i += 256) {
        int pp = i >> 8, c = i & 255;
        size_t o = ((size_t)b * NQ + qd[pp]) * 256 + c;
        tile[pp][c] = (float)latH[o] + (float)latL[o] * (1.0f / 2048.0f);
    }
    __syncthreads();
    float* ob = out + (size_t)b * OUTC * HWc + (size_t)Cc * HWc;
    for (int i = tid; i < 256 * 32; i += 256) {
        int ch = i >> 5, j = i & 31;
        ob[(size_t)ch * HWc + pd[j]] = tile[j][ch];
    }
}

extern "C" void kernel_launch(void* const* d_in, const int* in_sizes, int n_in,
                              void* d_out, int out_size, void* d_ws, size_t ws_size,
                              hipStream_t stream) {
    const float* x    = (const float*)d_in[0];
    const int*   mask = (const int*)d_in[1];
    float* out = (float*)d_out;
    char*  ws  = (char*)d_ws;

    _Float16* latH = (_Float16*)(ws);                    // 12,582,912 B
    _Float16* latL = (_Float16*)(ws + 12582912);         // 12,582,912 B
    _Float16* forH = (_Float16*)(ws + 25165824);         //  4,194,304 B
    _Float16* forL = (_Float16*)(ws + 29360128);         //  4,194,304 B
    float* invn    = (float*)(ws + 33554432);            //    131,072 B
    float* invnC   = (float*)(ws + 33685504);            //     98,304 B
    float* bv1     = (float*)(ws + 33783808);            //    262,144 B
    int*   bi1     = (int*)  (ws + 34045952);            //    262,144 B
    float* bv2     = (float*)(ws + 34308096);            //    262,144 B
    int*   bfin    = (int*)  (ws + 34570240);            //     32,768 B
    int*   pidx    = (int*)  (ws + 34603008);            //      4,096 B
    int*   qinv    = (int*)  (ws + 34607104);            //     16,384 B
    int*   pinv    = (int*)  (ws + 34623488);            //     16,384 B
    int*   cnt     = (int*)  (ws + 34639872);            //         32 B
    int*   fixrows = (int*)  (ws + 34639904);            //      2,048 B
    float* fixv    = (float*)(ws + 34641952);            //      8,192 B
    int*   fixi    = (int*)  (ws + 34650144);            //      8,192 B

    k_build<<<1, 1024, 0, stream>>>(mask, pidx, qinv, pinv, cnt);
    k_prep<<<1024, 256, 0, stream>>>(x, pinv, qinv, latH, latL, forH, forL, invn, invnC, out);
    k_gemm<<<dim3(4, QG, BZc), 512, 0, stream>>>(latH, latL, forH, forL, invnC, bv1, bi1, bv2);
    k_reduce<<<(BZc * NP + 255) / 256, 256, 0, stream>>>(bv1, bi1, bv2, bfin, cnt, fixrows);
    k_fixA<<<dim3(4, FIXSLOTS, BZc), 256, 0, stream>>>(x, pidx, mask, invn, cnt, fixrows, fixv, fixi);
    k_fixB<<<1, 512, 0, stream>>>(cnt, fixrows, fixv, fixi, qinv, bfin);
    k_scatter<<<dim3(32, BZc), 256, 0, stream>>>(latH, latL, bfin, pidx, out);
}

// Round 8
// 112.661 us; speedup vs baseline: 4.6692x; 1.0047x over previous
//
#include <hip/hip_runtime.h>
#include <math.h>

#define BZc 8
#define Cc 512
#define C2c 256
#define HWc 4096
#define OUTC 768
#define NP 1024
#define NQ 3072
#define QG 8        // q groups (chunks) for gemm: 384 q each
#define TAU 5e-5f
#define FIXSLOTS 64

typedef _Float16 h8 __attribute__((ext_vector_type(8)));
typedef float f16v __attribute__((ext_vector_type(16)));
typedef float f32x4 __attribute__((ext_vector_type(4)));

// ---------------- K0: compacted index lists + inverse maps + zero counters -------
__global__ __launch_bounds__(1024) void k_build(const int* __restrict__ mask,
                                                int* __restrict__ pidx,
                                                int* __restrict__ qinv,
                                                int* __restrict__ pinv,
                                                int* __restrict__ cnt) {
    __shared__ int s0[1024], s1[1024], t0[1024], t1[1024];
    int t = threadIdx.x;
    if (t < 8) cnt[t] = 0;
    int f[4];
    int cp = 0;
#pragma unroll
    for (int j = 0; j < 4; ++j) { f[j] = mask[t * 4 + j]; cp += f[j]; }
    s0[t] = cp; s1[t] = 4 - cp;
    __syncthreads();
    int *a = s0, *b = s1, *c = t0, *d = t1;
    for (int off = 1; off < 1024; off <<= 1) {
        int vp = a[t] + (t >= off ? a[t - off] : 0);
        int vq = b[t] + (t >= off ? b[t - off] : 0);
        c[t] = vp; d[t] = vq;
        __syncthreads();
        int* tmp;
        tmp = a; a = c; c = tmp;
        tmp = b; b = d; d = tmp;
    }
    int ep = a[t] - cp;
    int eq = b[t] - (4 - cp);
#pragma unroll
    for (int j = 0; j < 4; ++j) {
        int idx = t * 4 + j;
        if (f[j]) { pidx[ep] = idx; pinv[idx] = ep; qinv[idx] = -1; ep++; }
        else      { qinv[idx] = eq; pinv[idx] = -1; eq++; }
    }
}

// ---------------- K1: unified prep — reg-prefetch, deferred copy stores ----------
// blocks 0..511: latter -> latH/latL split (unmasked rows), invn/invnC, out copy.
// blocks 512..1023: former -> forH/forL split (masked rows), out copy + zero shift.
__global__ __launch_bounds__(256) void k_prep(const float* __restrict__ x,
                                              const int* __restrict__ pinv,
                                              const int* __restrict__ qinv,
                                              _Float16* __restrict__ latH,
                                              _Float16* __restrict__ latL,
                                              _Float16* __restrict__ forH,
                                              _Float16* __restrict__ forL,
                                              float* __restrict__ invn,
                                              float* __restrict__ invnC,
                                              float* __restrict__ out) {
    int id = blockIdx.x;
    bool isLat = id < 512;
    int b = isLat ? (id >> 6) : ((id - 512) >> 6);
    int g = isLat ? (id & 63) : ((id - 512) & 63);
    int tid = threadIdx.x;
    __shared__ float tile[64][65];   // [local ch][col]
    __shared__ float ssq[16][65];
    __shared__ int rowm[64];
    if (tid < 64) rowm[tid] = isLat ? qinv[g * 64 + tid] : pinv[g * 64 + tid];
    const float* xb = x + (size_t)b * Cc * HWc + (isLat ? (size_t)C2c * HWc : 0);
    float* ob = out + (size_t)b * OUTC * HWc + (isLat ? (size_t)C2c * HWc : 0);
    _Float16* dH = isLat ? latH + (size_t)b * NQ * 256 : forH + (size_t)b * NP * 256;
    _Float16* dL = isLat ? latL + (size_t)b * NQ * 256 : forL + (size_t)b * NP * 256;

    int cr = tid >> 4;           // 0..15: channel row within a 16-ch group
    int c4 = (tid & 15) * 4;     // column quad

    f32x4 vv[4][4];              // [chunk][p] staged x values (64 VGPR)
    // prologue: load chunk 0
#pragma unroll
    for (int p = 0; p < 4; ++p)
        vv[0][p] = *(const f32x4*)(xb + (size_t)(p * 16 + cr) * HWc + g * 64 + c4);
    __syncthreads();             // rowm visible

    int qq = tid >> 2, sub = tid & 3;
    int dr = rowm[qq];

#pragma unroll
    for (int c = 0; c < 4; ++c) {
        int c0 = c * 64;
        // tile write from registers (no vmem dependency beyond the staged loads)
#pragma unroll
        for (int p = 0; p < 4; ++p) {
            int lch = p * 16 + cr;
            f32x4 v = vv[c][p];
            tile[lch][c4]     = v.x;
            tile[lch][c4 + 1] = v.y;
            tile[lch][c4 + 2] = v.z;
            tile[lch][c4 + 3] = v.w;
        }
        __syncthreads();
        // prefetch next chunk — completes under the split phase below
        if (c < 3) {
#pragma unroll
            for (int p = 0; p < 4; ++p)
                vv[c + 1][p] = *(const f32x4*)(xb + (size_t)(c0 + 64 + p * 16 + cr) * HWc + g * 64 + c4);
        }
        // split: thread (qq, sub) emits 16 ch (h8 hi/lo pair) for column qq
        if (dr >= 0) {
            h8 hv0, hv1, lv0, lv1;
#pragma unroll
            for (int j = 0; j < 8; ++j) {
                float v = tile[sub * 16 + j][qq];
                _Float16 h = (_Float16)v;
                hv0[j] = h; lv0[j] = (_Float16)((v - (float)h) * 2048.0f);
            }
#pragma unroll
            for (int j = 0; j < 8; ++j) {
                float v = tile[sub * 16 + 8 + j][qq];
                _Float16 h = (_Float16)v;
                hv1[j] = h; lv1[j] = (_Float16)((v - (float)h) * 2048.0f);
            }
            size_t o = (size_t)dr * 256 + c0 + sub * 16;
            *(h8*)(dH + o) = hv0; *(h8*)(dH + o + 8) = hv1;
            *(h8*)(dL + o) = lv0; *(h8*)(dL + o + 8) = lv1;
        }
        __syncthreads();
    }

    // epilogue: deferred out-copy (nt stores never gate a barrier)
#pragma unroll
    for (int c = 0; c < 4; ++c)
#pragma unroll
        for (int p = 0; p < 4; ++p) {
            int ch = c * 64 + p * 16 + cr;
            __builtin_nontemporal_store(vv[c][p], (f32x4*)(ob + (size_t)ch * HWc + g * 64 + c4));
        }

    if (isLat) {
        float s0 = 0.f, s1 = 0.f, s2 = 0.f, s3 = 0.f;
#pragma unroll
        for (int c = 0; c < 4; ++c)
#pragma unroll
            for (int p = 0; p < 4; ++p) {
                f32x4 v = vv[c][p];
                s0 = fmaf(v.x, v.x, s0); s1 = fmaf(v.y, v.y, s1);
                s2 = fmaf(v.z, v.z, s2); s3 = fmaf(v.w, v.w, s3);
            }
        ssq[cr][c4] = s0; ssq[cr][c4 + 1] = s1; ssq[cr][c4 + 2] = s2; ssq[cr][c4 + 3] = s3;
        __syncthreads();
        if (tid < 64) {
            float s = 0.f;
#pragma unroll
            for (int r = 0; r < 16; ++r) s += ssq[r][tid];
            float inv = 1.0f / (sqrtf(s) + 1e-8f);
            int q = g * 64 + tid;
            invn[b * HWc + q] = inv;
            int qc = rowm[tid];
            if (qc >= 0) invnC[b * NQ + qc] = inv;
        }
    } else {
        // zero the shift region for my 64 columns (scatter overwrites masked later)
        f32x4 z = {0.f, 0.f, 0.f, 0.f};
        float* sb = out + (size_t)b * OUTC * HWc + (size_t)Cc * HWc;
        for (int i = tid; i < 256 * 16; i += 256) {
            int ch = i >> 4, j4 = i & 15;
            __builtin_nontemporal_store(z, (f32x4*)(sb + (size_t)ch * HWc + g * 64 + j4 * 4));
        }
    }
}

// ---------------- K2: MFMA fp16x2 GEMM (raw) + invn epilogue + per-chunk top-2 ---
__global__ __launch_bounds__(512, 2) void k_gemm(const _Float16* __restrict__ latH,
                                                 const _Float16* __restrict__ latL,
                                                 const _Float16* __restrict__ forH,
                                                 const _Float16* __restrict__ forL,
                                                 const float* __restrict__ invnC,
                                                 float* __restrict__ bv1,
                                                 int* __restrict__ bi1,
                                                 float* __restrict__ bv2) {
    int pg = blockIdx.x;
    int qg = blockIdx.y;
    int b  = blockIdx.z;
    int tid = threadIdx.x;
    int w = tid >> 6, lane = tid & 63;
    int l31 = lane & 31, lh = lane >> 5;

    __shared__ __align__(16) _Float16 sH[2][32 * 256];
    __shared__ __align__(16) _Float16 sL[2][32 * 256];
    __shared__ float sInv[384];

    if (tid < 384) sInv[tid] = invnC[b * NQ + qg * 384 + tid];

    size_t fo = ((size_t)(b * NP + pg * 256 + w * 32 + l31)) * 256 + lh * 8;
    const _Float16* fH = forH + fo;
    const _Float16* fL = forL + fo;
    h8 BH[16], BL[16];
#pragma unroll
    for (int ks = 0; ks < 16; ++ks) {
        BH[ks] = *(const h8*)(fH + ks * 16);
        BL[ks] = *(const h8*)(fL + ks * 16);
    }

    const _Float16* latHb = latH + (size_t)(b * NQ + qg * 384) * 256;
    const _Float16* latLb = latL + (size_t)(b * NQ + qg * 384) * 256;
    int sq0 = tid >> 5;
    int sq1 = 16 + (tid >> 5);
    int ssl = tid & 31;

    float v1 = -INFINITY, v2 = -INFINITY; int i1 = 0;

    f32x4 rH0, rH1, rL0, rL1;
#define LOADQ(t)                                                                   \
    rH0 = *(const f32x4*)(latHb + ((size_t)((t) * 32 + sq0) * 256 + ssl * 8));     \
    rH1 = *(const f32x4*)(latHb + ((size_t)((t) * 32 + sq1) * 256 + ssl * 8));     \
    rL0 = *(const f32x4*)(latLb + ((size_t)((t) * 32 + sq0) * 256 + ssl * 8));     \
    rL1 = *(const f32x4*)(latLb + ((size_t)((t) * 32 + sq1) * 256 + ssl * 8));
#define WRITEQ(bf)                                                                 \
    *(f32x4*)(&sH[bf][sq0 * 256 + ((ssl ^ sq0) * 8)]) = rH0;                       \
    *(f32x4*)(&sH[bf][sq1 * 256 + ((ssl ^ sq1) * 8)]) = rH1;                       \
    *(f32x4*)(&sL[bf][sq0 * 256 + ((ssl ^ sq0) * 8)]) = rL0;                       \
    *(f32x4*)(&sL[bf][sq1 * 256 + ((ssl ^ sq1) * 8)]) = rL1;

    LOADQ(0); WRITEQ(0);
    __syncthreads();

    for (int t = 0; t < 12; ++t) {
        if (t < 11) { LOADQ(t + 1); }
        const _Float16* bufH = &sH[t & 1][0];
        const _Float16* bufL = &sL[t & 1][0];
        f16v accA = {}, accB = {};
#pragma unroll
        for (int ks = 0; ks < 16; ++ks) {
            int slotA = (ks * 2 + lh) ^ l31;
            h8 aH = *(const h8*)(bufH + l31 * 256 + slotA * 8);
            h8 aL = *(const h8*)(bufL + l31 * 256 + slotA * 8);
            accA = __builtin_amdgcn_mfma_f32_32x32x16_f16(aH, BH[ks], accA, 0, 0, 0);
            accB = __builtin_amdgcn_mfma_f32_32x32x16_f16(aH, BL[ks], accB, 0, 0, 0);
            accB = __builtin_amdgcn_mfma_f32_32x32x16_f16(aL, BH[ks], accB, 0, 0, 0);
        }
#pragma unroll
        for (int r = 0; r < 16; ++r) {
            int off = (r & 3) + 8 * (r >> 2) + 4 * lh;
            float v = (accA[r] + accB[r] * (1.0f / 2048.0f)) * sInv[t * 32 + off];
            int q = qg * 384 + t * 32 + off;
            if (v > v1) { v2 = v1; v1 = v; i1 = q; }
            else if (v > v2) { v2 = v; }
        }
        if (t < 11) { WRITEQ((t + 1) & 1); }
        __syncthreads();
    }
#undef LOADQ
#undef WRITEQ
    float ov1 = __shfl_xor(v1, 32);
    int   oi1 = __shfl_xor(i1, 32);
    float ov2 = __shfl_xor(v2, 32);
    if (ov1 > v1) { v2 = fmaxf(v1, ov2); v1 = ov1; i1 = oi1; }
    else          { v2 = fmaxf(ov1, v2); }
    if (lane < 32) {
        size_t o = ((size_t)b * NP + pg * 256 + w * 32 + lane) * QG + qg;
        bv1[o] = v1; bi1[o] = i1; bv2[o] = v2;
    }
}

// ---------------- K3: merge chunks -> best index + margin flag -------------------
__global__ void k_reduce(const float* __restrict__ bv1, const int* __restrict__ bi1,
                         const float* __restrict__ bv2, int* __restrict__ bfin,
                         int* __restrict__ cnt, int* __restrict__ fixrows) {
    int t = blockIdx.x * blockDim.x + threadIdx.x;
    if (t >= BZc * NP) return;
    float V1 = -INFINITY, V2 = -INFINITY; int I1 = 0;
    for (int c = 0; c < QG; ++c) {
        float a = bv1[(size_t)t * QG + c];
        float a2 = bv2[(size_t)t * QG + c];
        int   i = bi1[(size_t)t * QG + c];
        if (a > V1) { V2 = fmaxf(V1, a2); V1 = a; I1 = i; }
        else        { V2 = fmaxf(V2, a); }
    }
    bfin[t] = I1;
    if (V1 - V2 < TAU) {
        int b = t >> 10;
        int s = atomicAdd(&cnt[b], 1);
        if (s < FIXSLOTS) fixrows[b * FIXSLOTS + s] = t & 1023;
    }
}

// ---------------- K4a: exact fp32 fixup, phase A (per q-quarter partial argmax) --
__global__ __launch_bounds__(256) void k_fixA(const float* __restrict__ x,
                                              const int* __restrict__ pidx,
                                              const int* __restrict__ mask,
                                              const float* __restrict__ invn,
                                              const int* __restrict__ cnt,
                                              const int* __restrict__ fixrows,
                                              float* __restrict__ fixv,
                                              int* __restrict__ fixi) {
    int qg = blockIdx.x, s = blockIdx.y, b = blockIdx.z;
    int n = cnt[b]; if (n > FIXSLOTS) n = FIXSLOTS;
    if (s >= n) return;
    int p = fixrows[b * FIXSLOTS + s];
    int porig = pidx[p];
    int tid = threadIdx.x;
    __shared__ float fs[256];
    fs[tid] = x[((size_t)b * Cc + tid) * HWc + porig];
    __syncthreads();
    const float* lx = x + ((size_t)b * Cc + C2c) * HWc;
    int q0 = qg * 1024 + tid * 4;
    float4 acc = make_float4(0.f, 0.f, 0.f, 0.f);
    for (int c0 = 0; c0 < 256; c0 += 8) {
        float4 v[8];
#pragma unroll
        for (int u = 0; u < 8; ++u)
            v[u] = *(const float4*)(lx + (size_t)(c0 + u) * HWc + q0);
#pragma unroll
        for (int u = 0; u < 8; ++u) {
            float fc = fs[c0 + u];
            acc.x = fmaf(fc, v[u].x, acc.x);
            acc.y = fmaf(fc, v[u].y, acc.y);
            acc.z = fmaf(fc, v[u].z, acc.z);
            acc.w = fmaf(fc, v[u].w, acc.w);
        }
    }
    float vals[4] = {acc.x, acc.y, acc.z, acc.w};
    float bv = -INFINITY; int bq = 1 << 30;
#pragma unroll
    for (int k = 0; k < 4; ++k) {
        int q = q0 + k;
        float val = vals[k] * invn[b * HWc + q];
        if (mask[q] == 0 && val > bv) { bv = val; bq = q; }
    }
    __shared__ float rv[256]; __shared__ int rq[256];
    rv[tid] = bv; rq[tid] = bq; __syncthreads();
    for (int off = 128; off > 0; off >>= 1) {
        if (tid < off) {
            float v2 = rv[tid + off]; int q2 = rq[tid + off];
            if (v2 > rv[tid] || (v2 == rv[tid] && q2 < rq[tid])) { rv[tid] = v2; rq[tid] = q2; }
        }
        __syncthreads();
    }
    if (tid == 0) {
        fixv[(b * FIXSLOTS + s) * 4 + qg] = rv[0];
        fixi[(b * FIXSLOTS + s) * 4 + qg] = rq[0];
    }
}

// ---------------- K4b: fixup phase B — merge quarters, spatial->compact ----------
__global__ void k_fixB(const int* __restrict__ cnt, const int* __restrict__ fixrows,
                       const float* __restrict__ fixv, const int* __restrict__ fixi,
                       const int* __restrict__ qinv, int* __restrict__ bfin) {
    int t = threadIdx.x;                 // 512 threads: b = t>>6, s = t&63
    int b = t >> 6, s = t & 63;
    int n = cnt[b]; if (n > FIXSLOTS) n = FIXSLOTS;
    if (s >= n) return;
    float bv = -INFINITY; int bq = 1 << 30;
    for (int qg = 0; qg < 4; ++qg) {
        float v = fixv[(b * FIXSLOTS + s) * 4 + qg];
        int   q = fixi[(b * FIXSLOTS + s) * 4 + qg];
        if (v > bv || (v == bv && q < bq)) { bv = v; bq = q; }
    }
    int p = fixrows[b * FIXSLOTS + s];
    bfin[b * NP + p] = qinv[bq];
}

// ---------------- K5: gather best latter vectors into shift region ---------------
__global__ __launch_bounds__(256) void k_scatter(const _Float16* __restrict__ latH,
                                                 const _Float16* __restrict__ latL,
                                                 const int* __restrict__ bfin,
                                                 const int* __restrict__ pidx,
                                                 float* __restrict__ out) {
    int blk = blockIdx.x;
    int b   = blockIdx.y;
    int tid = threadIdx.x;
    __shared__ float tile[32][257];
    __shared__ int qd[32], pd[32];
    if (tid < 32) {
        qd[tid] = bfin[b * NP + blk * 32 + tid];
        pd[tid] = pidx[blk * 32 + tid];
    }
    __syncthreads();
    for (int i = tid; i < 32 * 256; i += 256) {
        int pp = i >> 8, c = i & 255;
        size_t o = ((size_t)b * NQ + qd[pp]) * 256 + c;
        tile[pp][c] = (float)latH[o] + (float)latL[o] * (1.0f / 2048.0f);
    }
    __syncthreads();
    float* ob = out + (size_t)b * OUTC * HWc + (size_t)Cc * HWc;
    for (int i = tid; i < 256 * 32; i += 256) {
        int ch = i >> 5, j = i & 31;
        ob[(size_t)ch * HWc + pd[j]] = tile[j][ch];
    }
}

extern "C" void kernel_launch(void* const* d_in, const int* in_sizes, int n_in,
                              void* d_out, int out_size, void* d_ws, size_t ws_size,
                              hipStream_t stream) {
    const float* x    = (const float*)d_in[0];
    const int*   mask = (const int*)d_in[1];
    float* out = (float*)d_out;
    char*  ws  = (char*)d_ws;

    _Float16* latH = (_Float16*)(ws);                    // 12,582,912 B
    _Float16* latL = (_Float16*)(ws + 12582912);         // 12,582,912 B
    _Float16* forH = (_Float16*)(ws + 25165824);         //  4,194,304 B
    _Float16* forL = (_Float16*)(ws + 29360128);         //  4,194,304 B
    float* invn    = (float*)(ws + 33554432);            //    131,072 B
    float* invnC   = (float*)(ws + 33685504);            //     98,304 B
    float* bv1     = (float*)(ws + 33783808);            //    262,144 B
    int*   bi1     = (int*)  (ws + 34045952);            //    262,144 B
    float* bv2     = (float*)(ws + 34308096);            //    262,144 B
    int*   bfin    = (int*)  (ws + 34570240);            //     32,768 B
    int*   pidx    = (int*)  (ws + 34603008);            //      4,096 B
    int*   qinv    = (int*)  (ws + 34607104);            //     16,384 B
    int*   pinv    = (int*)  (ws + 34623488);            //     16,384 B
    int*   cnt     = (int*)  (ws + 34639872);            //         32 B
    int*   fixrows = (int*)  (ws + 34639904);            //      2,048 B
    float* fixv    = (float*)(ws + 34641952);            //      8,192 B
    int*   fixi    = (int*)  (ws + 34650144);            //      8,192 B

    k_build<<<1, 1024, 0, stream>>>(mask, pidx, qinv, pinv, cnt);
    k_prep<<<1024, 256, 0, stream>>>(x, pinv, qinv, latH, latL, forH, forL, invn, invnC, out);
    k_gemm<<<dim3(4, QG, BZc), 512, 0, stream>>>(latH, latL, forH, forL, invnC, bv1, bi1, bv2);
    k_reduce<<<(BZc * NP + 255) / 256, 256, 0, stream>>>(bv1, bi1, bv2, bfin, cnt, fixrows);
    k_fixA<<<dim3(4, FIXSLOTS, BZc), 256, 0, stream>>>(x, pidx, mask, invn, cnt, fixrows, fixv, fixi);
    k_fixB<<<1, 512, 0, stream>>>(cnt, fixrows, fixv, fixi, qinv, bfin);
    k_scatter<<<dim3(32, BZc), 256, 0, stream>>>(latH, latL, bfin, pidx, out);
}

// Round 9
// 112.107 us; speedup vs baseline: 4.6923x; 1.0049x over previous
//
#include <hip/hip_runtime.h>
#include <math.h>

#define BZc 8
#define Cc 512
#define C2c 256
#define HWc 4096
#define OUTC 768
#define NP 1024
#define NQ 3072
#define QG 8        // q groups (chunks) for gemm: 384 q each
#define TAU 5e-5f
#define FIXSLOTS 64

typedef _Float16 h8 __attribute__((ext_vector_type(8)));
typedef float f16v __attribute__((ext_vector_type(16)));
typedef float f32x4 __attribute__((ext_vector_type(4)));

// ---------------- K0: compacted index lists + inverse maps + zero counters -------
__global__ __launch_bounds__(1024) void k_build(const int* __restrict__ mask,
                                                int* __restrict__ pidx,
                                                int* __restrict__ qinv,
                                                int* __restrict__ pinv,
                                                int* __restrict__ cnt) {
    __shared__ int s0[1024], s1[1024], t0[1024], t1[1024];
    int t = threadIdx.x;
    if (t < 8) cnt[t] = 0;
    int f[4];
    int cp = 0;
#pragma unroll
    for (int j = 0; j < 4; ++j) { f[j] = mask[t * 4 + j]; cp += f[j]; }
    s0[t] = cp; s1[t] = 4 - cp;
    __syncthreads();
    int *a = s0, *b = s1, *c = t0, *d = t1;
    for (int off = 1; off < 1024; off <<= 1) {
        int vp = a[t] + (t >= off ? a[t - off] : 0);
        int vq = b[t] + (t >= off ? b[t - off] : 0);
        c[t] = vp; d[t] = vq;
        __syncthreads();
        int* tmp;
        tmp = a; a = c; c = tmp;
        tmp = b; b = d; d = tmp;
    }
    int ep = a[t] - cp;
    int eq = b[t] - (4 - cp);
#pragma unroll
    for (int j = 0; j < 4; ++j) {
        int idx = t * 4 + j;
        if (f[j]) { pidx[ep] = idx; pinv[idx] = ep; qinv[idx] = -1; ep++; }
        else      { qinv[idx] = eq; pinv[idx] = -1; eq++; }
    }
}

// ---------------- K1: prep v3 — 2048 blocks (32 cols each) for occupancy ---------
// blocks 0..1023: latter (b=id>>7, 32 spatial cols each) -> latH/latL split
//   (unmasked rows), invn/invnC, out[256:512) copy.
// blocks 1024..2047: former -> forH/forL split (masked rows), out[0:256) copy,
//   zero out[512:768).
__global__ __launch_bounds__(256) void k_prep(const float* __restrict__ x,
                                              const int* __restrict__ pinv,
                                              const int* __restrict__ qinv,
                                              _Float16* __restrict__ latH,
                                              _Float16* __restrict__ latL,
                                              _Float16* __restrict__ forH,
                                              _Float16* __restrict__ forL,
                                              float* __restrict__ invn,
                                              float* __restrict__ invnC,
                                              float* __restrict__ out) {
    int id = blockIdx.x;
    bool isLat = id < 1024;
    int rid = isLat ? id : id - 1024;
    int b = rid >> 7;
    int g = rid & 127;           // 32-col group
    int col0 = g * 32;
    int tid = threadIdx.x;
    __shared__ float tile[64][33];   // [local ch][col]
    __shared__ float ssq[32][33];
    __shared__ int rowm[32];
    if (tid < 32) rowm[tid] = isLat ? qinv[col0 + tid] : pinv[col0 + tid];
    const float* xb = x + (size_t)b * Cc * HWc + (isLat ? (size_t)C2c * HWc : 0);
    float* ob = out + (size_t)b * OUTC * HWc + (isLat ? (size_t)C2c * HWc : 0);
    _Float16* dH = isLat ? latH + (size_t)b * NQ * 256 : forH + (size_t)b * NP * 256;
    _Float16* dL = isLat ? latL + (size_t)b * NQ * 256 : forL + (size_t)b * NP * 256;

    int cr = tid >> 3;           // 0..31: channel row within 32-ch half
    int c4 = (tid & 7) * 4;      // column quad (0..28)

    f32x4 vv[4][2];              // [chunk][half] staged x values (32 VGPR)
    // prologue: load chunk 0 (channels 0..63)
    vv[0][0] = *(const f32x4*)(xb + (size_t)cr * HWc + col0 + c4);
    vv[0][1] = *(const f32x4*)(xb + (size_t)(32 + cr) * HWc + col0 + c4);
    __syncthreads();             // rowm visible

    int qq = tid >> 3, sub = tid & 7;
    int dr = rowm[qq];

#pragma unroll
    for (int c = 0; c < 4; ++c) {
        int ch0 = c * 64;
        // tile write from registers
        {
            f32x4 v0 = vv[c][0], v1 = vv[c][1];
            tile[cr][c4]      = v0.x; tile[cr][c4 + 1]      = v0.y;
            tile[cr][c4 + 2]  = v0.z; tile[cr][c4 + 3]      = v0.w;
            tile[32 + cr][c4] = v1.x; tile[32 + cr][c4 + 1] = v1.y;
            tile[32 + cr][c4 + 2] = v1.z; tile[32 + cr][c4 + 3] = v1.w;
        }
        __syncthreads();
        // prefetch next chunk — completes under the split phase below
        if (c < 3) {
            vv[c + 1][0] = *(const f32x4*)(xb + (size_t)(ch0 + 64 + cr) * HWc + col0 + c4);
            vv[c + 1][1] = *(const f32x4*)(xb + (size_t)(ch0 + 96 + cr) * HWc + col0 + c4);
        }
        // split: thread (qq, sub) emits 8 ch (one h8 hi/lo pair) for column qq
        if (dr >= 0) {
            h8 hv, lv;
#pragma unroll
            for (int j = 0; j < 8; ++j) {
                float v = tile[sub * 8 + j][qq];
                _Float16 h = (_Float16)v;
                hv[j] = h; lv[j] = (_Float16)((v - (float)h) * 2048.0f);
            }
            size_t o = (size_t)dr * 256 + ch0 + sub * 8;
            *(h8*)(dH + o) = hv;
            *(h8*)(dL + o) = lv;
        }
        __syncthreads();
    }

    // epilogue: deferred out-copy (nt stores never gate a barrier)
#pragma unroll
    for (int c = 0; c < 4; ++c) {
        __builtin_nontemporal_store(vv[c][0], (f32x4*)(ob + (size_t)(c * 64 + cr) * HWc + col0 + c4));
        __builtin_nontemporal_store(vv[c][1], (f32x4*)(ob + (size_t)(c * 64 + 32 + cr) * HWc + col0 + c4));
    }

    if (isLat) {
        float s0 = 0.f, s1 = 0.f, s2 = 0.f, s3 = 0.f;
#pragma unroll
        for (int c = 0; c < 4; ++c)
#pragma unroll
            for (int p = 0; p < 2; ++p) {
                f32x4 v = vv[c][p];
                s0 = fmaf(v.x, v.x, s0); s1 = fmaf(v.y, v.y, s1);
                s2 = fmaf(v.z, v.z, s2); s3 = fmaf(v.w, v.w, s3);
            }
        ssq[cr][c4] = s0; ssq[cr][c4 + 1] = s1; ssq[cr][c4 + 2] = s2; ssq[cr][c4 + 3] = s3;
        __syncthreads();
        if (tid < 32) {
            float s = 0.f;
#pragma unroll
            for (int r = 0; r < 32; ++r) s += ssq[r][tid];
            float inv = 1.0f / (sqrtf(s) + 1e-8f);
            invn[b * HWc + col0 + tid] = inv;
            int qc = rowm[tid];
            if (qc >= 0) invnC[b * NQ + qc] = inv;
        }
    } else {
        // zero the shift region for my 32 columns (scatter overwrites masked later)
        f32x4 z = {0.f, 0.f, 0.f, 0.f};
        float* sb = out + (size_t)b * OUTC * HWc + (size_t)Cc * HWc;
        for (int i = tid; i < 256 * 8; i += 256) {
            int ch = i >> 3, j4 = i & 7;
            __builtin_nontemporal_store(z, (f32x4*)(sb + (size_t)ch * HWc + col0 + j4 * 4));
        }
    }
}

// ---------------- K2: MFMA fp16x2 GEMM (raw) + invn epilogue + per-chunk top-2 ---
__global__ __launch_bounds__(512, 2) void k_gemm(const _Float16* __restrict__ latH,
                                                 const _Float16* __restrict__ latL,
                                                 const _Float16* __restrict__ forH,
                                                 const _Float16* __restrict__ forL,
                                                 const float* __restrict__ invnC,
                                                 float* __restrict__ bv1,
                                                 int* __restrict__ bi1,
                                                 float* __restrict__ bv2) {
    int pg = blockIdx.x;
    int qg = blockIdx.y;
    int b  = blockIdx.z;
    int tid = threadIdx.x;
    int w = tid >> 6, lane = tid & 63;
    int l31 = lane & 31, lh = lane >> 5;

    __shared__ __align__(16) _Float16 sH[2][32 * 256];
    __shared__ __align__(16) _Float16 sL[2][32 * 256];
    __shared__ float sInv[384];

    if (tid < 384) sInv[tid] = invnC[b * NQ + qg * 384 + tid];

    size_t fo = ((size_t)(b * NP + pg * 256 + w * 32 + l31)) * 256 + lh * 8;
    const _Float16* fH = forH + fo;
    const _Float16* fL = forL + fo;
    h8 BH[16], BL[16];
#pragma unroll
    for (int ks = 0; ks < 16; ++ks) {
        BH[ks] = *(const h8*)(fH + ks * 16);
        BL[ks] = *(const h8*)(fL + ks * 16);
    }

    const _Float16* latHb = latH + (size_t)(b * NQ + qg * 384) * 256;
    const _Float16* latLb = latL + (size_t)(b * NQ + qg * 384) * 256;
    int sq0 = tid >> 5;
    int sq1 = 16 + (tid >> 5);
    int ssl = tid & 31;

    float v1 = -INFINITY, v2 = -INFINITY; int i1 = 0;

    f32x4 rH0, rH1, rL0, rL1;
#define LOADQ(t)                                                                   \
    rH0 = *(const f32x4*)(latHb + ((size_t)((t) * 32 + sq0) * 256 + ssl * 8));     \
    rH1 = *(const f32x4*)(latHb + ((size_t)((t) * 32 + sq1) * 256 + ssl * 8));     \
    rL0 = *(const f32x4*)(latLb + ((size_t)((t) * 32 + sq0) * 256 + ssl * 8));     \
    rL1 = *(const f32x4*)(latLb + ((size_t)((t) * 32 + sq1) * 256 + ssl * 8));
#define WRITEQ(bf)                                                                 \
    *(f32x4*)(&sH[bf][sq0 * 256 + ((ssl ^ sq0) * 8)]) = rH0;                       \
    *(f32x4*)(&sH[bf][sq1 * 256 + ((ssl ^ sq1) * 8)]) = rH1;                       \
    *(f32x4*)(&sL[bf][sq0 * 256 + ((ssl ^ sq0) * 8)]) = rL0;                       \
    *(f32x4*)(&sL[bf][sq1 * 256 + ((ssl ^ sq1) * 8)]) = rL1;

    LOADQ(0); WRITEQ(0);
    __syncthreads();

    for (int t = 0; t < 12; ++t) {
        if (t < 11) { LOADQ(t + 1); }
        const _Float16* bufH = &sH[t & 1][0];
        const _Float16* bufL = &sL[t & 1][0];
        f16v accA = {}, accB = {};
#pragma unroll
        for (int ks = 0; ks < 16; ++ks) {
            int slotA = (ks * 2 + lh) ^ l31;
            h8 aH = *(const h8*)(bufH + l31 * 256 + slotA * 8);
            h8 aL = *(const h8*)(bufL + l31 * 256 + slotA * 8);
            accA = __builtin_amdgcn_mfma_f32_32x32x16_f16(aH, BH[ks], accA, 0, 0, 0);
            accB = __builtin_amdgcn_mfma_f32_32x32x16_f16(aH, BL[ks], accB, 0, 0, 0);
            accB = __builtin_amdgcn_mfma_f32_32x32x16_f16(aL, BH[ks], accB, 0, 0, 0);
        }
#pragma unroll
        for (int r = 0; r < 16; ++r) {
            int off = (r & 3) + 8 * (r >> 2) + 4 * lh;
            float v = (accA[r] + accB[r] * (1.0f / 2048.0f)) * sInv[t * 32 + off];
            int q = qg * 384 + t * 32 + off;
            if (v > v1) { v2 = v1; v1 = v; i1 = q; }
            else if (v > v2) { v2 = v; }
        }
        if (t < 11) { WRITEQ((t + 1) & 1); }
        __syncthreads();
    }
#undef LOADQ
#undef WRITEQ
    float ov1 = __shfl_xor(v1, 32);
    int   oi1 = __shfl_xor(i1, 32);
    float ov2 = __shfl_xor(v2, 32);
    if (ov1 > v1) { v2 = fmaxf(v1, ov2); v1 = ov1; i1 = oi1; }
    else          { v2 = fmaxf(ov1, v2); }
    if (lane < 32) {
        size_t o = ((size_t)b * NP + pg * 256 + w * 32 + lane) * QG + qg;
        bv1[o] = v1; bi1[o] = i1; bv2[o] = v2;
    }
}

// ---------------- K3: merge chunks -> best index + margin flag -------------------
__global__ void k_reduce(const float* __restrict__ bv1, const int* __restrict__ bi1,
                         const float* __restrict__ bv2, int* __restrict__ bfin,
                         int* __restrict__ cnt, int* __restrict__ fixrows) {
    int t = blockIdx.x * blockDim.x + threadIdx.x;
    if (t >= BZc * NP) return;
    float V1 = -INFINITY, V2 = -INFINITY; int I1 = 0;
    for (int c = 0; c < QG; ++c) {
        float a = bv1[(size_t)t * QG + c];
        float a2 = bv2[(size_t)t * QG + c];
        int   i = bi1[(size_t)t * QG + c];
        if (a > V1) { V2 = fmaxf(V1, a2); V1 = a; I1 = i; }
        else        { V2 = fmaxf(V2, a); }
    }
    bfin[t] = I1;
    if (V1 - V2 < TAU) {
        int b = t >> 10;
        int s = atomicAdd(&cnt[b], 1);
        if (s < FIXSLOTS) fixrows[b * FIXSLOTS + s] = t & 1023;
    }
}

// ---------------- K4a: exact fp32 fixup, phase A (per q-quarter partial argmax) --
__global__ __launch_bounds__(256) void k_fixA(const float* __restrict__ x,
                                              const int* __restrict__ pidx,
                                              const int* __restrict__ mask,
                                              const float* __restrict__ invn,
                                              const int* __restrict__ cnt,
                                              const int* __restrict__ fixrows,
                                              float* __restrict__ fixv,
                                              int* __restrict__ fixi) {
    int qg = blockIdx.x, s = blockIdx.y, b = blockIdx.z;
    int n = cnt[b]; if (n > FIXSLOTS) n = FIXSLOTS;
    if (s >= n) return;
    int p = fixrows[b * FIXSLOTS + s];
    int porig = pidx[p];
    int tid = threadIdx.x;
    __shared__ float fs[256];
    fs[tid] = x[((size_t)b * Cc + tid) * HWc + porig];
    __syncthreads();
    const float* lx = x + ((size_t)b * Cc + C2c) * HWc;
    int q0 = qg * 1024 + tid * 4;
    float4 acc = make_float4(0.f, 0.f, 0.f, 0.f);
    for (int c0 = 0; c0 < 256; c0 += 8) {
        float4 v[8];
#pragma unroll
        for (int u = 0; u < 8; ++u)
            v[u] = *(const float4*)(lx + (size_t)(c0 + u) * HWc + q0);
#pragma unroll
        for (int u = 0; u < 8; ++u) {
            float fc = fs[c0 + u];
            acc.x = fmaf(fc, v[u].x, acc.x);
            acc.y = fmaf(fc, v[u].y, acc.y);
            acc.z = fmaf(fc, v[u].z, acc.z);
            acc.w = fmaf(fc, v[u].w, acc.w);
        }
    }
    float vals[4] = {acc.x, acc.y, acc.z, acc.w};
    float bv = -INFINITY; int bq = 1 << 30;
#pragma unroll
    for (int k = 0; k < 4; ++k) {
        int q = q0 + k;
        float val = vals[k] * invn[b * HWc + q];
        if (mask[q] == 0 && val > bv) { bv = val; bq = q; }
    }
    __shared__ float rv[256]; __shared__ int rq[256];
    rv[tid] = bv; rq[tid] = bq; __syncthreads();
    for (int off = 128; off > 0; off >>= 1) {
        if (tid < off) {
            float v2 = rv[tid + off]; int q2 = rq[tid + off];
            if (v2 > rv[tid] || (v2 == rv[tid] && q2 < rq[tid])) { rv[tid] = v2; rq[tid] = q2; }
        }
        __syncthreads();
    }
    if (tid == 0) {
        fixv[(b * FIXSLOTS + s) * 4 + qg] = rv[0];
        fixi[(b * FIXSLOTS + s) * 4 + qg] = rq[0];
    }
}

// ---------------- K4b: fixup phase B — merge quarters, spatial->compact ----------
__global__ void k_fixB(const int* __restrict__ cnt, const int* __restrict__ fixrows,
                       const float* __restrict__ fixv, const int* __restrict__ fixi,
                       const int* __restrict__ qinv, int* __restrict__ bfin) {
    int t = threadIdx.x;                 // 512 threads: b = t>>6, s = t&63
    int b = t >> 6, s = t & 63;
    int n = cnt[b]; if (n > FIXSLOTS) n = FIXSLOTS;
    if (s >= n) return;
    float bv = -INFINITY; int bq = 1 << 30;
    for (int qg = 0; qg < 4; ++qg) {
        float v = fixv[(b * FIXSLOTS + s) * 4 + qg];
        int   q = fixi[(b * FIXSLOTS + s) * 4 + qg];
        if (v > bv || (v == bv && q < bq)) { bv = v; bq = q; }
    }
    int p = fixrows[b * FIXSLOTS + s];
    bfin[b * NP + p] = qinv[bq];
}

// ---------------- K5: gather best latter vectors into shift region ---------------
__global__ __launch_bounds__(256) void k_scatter(const _Float16* __restrict__ latH,
                                                 const _Float16* __restrict__ latL,
                                                 const int* __restrict__ bfin,
                                                 const int* __restrict__ pidx,
                                                 float* __restrict__ out) {
    int blk = blockIdx.x;
    int b   = blockIdx.y;
    int tid = threadIdx.x;
    __shared__ float tile[32][257];
    __shared__ int qd[32], pd[32];
    if (tid < 32) {
        qd[tid] = bfin[b * NP + blk * 32 + tid];
        pd[tid] = pidx[blk * 32 + tid];
    }
    __syncthreads();
    for (int i = tid; i < 32 * 256; i += 256) {
        int pp = i >> 8, c = i & 255;
        size_t o = ((size_t)b * NQ + qd[pp]) * 256 + c;
        tile[pp][c] = (float)latH[o] + (float)latL[o] * (1.0f / 2048.0f);
    }
    __syncthreads();
    float* ob = out + (size_t)b * OUTC * HWc + (size_t)Cc * HWc;
    for (int i = tid; i < 256 * 32; i += 256) {
        int ch = i >> 5, j = i & 31;
        ob[(size_t)ch * HWc + pd[j]] = tile[j][ch];
    }
}

extern "C" void kernel_launch(void* const* d_in, const int* in_sizes, int n_in,
                              void* d_out, int out_size, void* d_ws, size_t ws_size,
                              hipStream_t stream) {
    const float* x    = (const float*)d_in[0];
    const int*   mask = (const int*)d_in[1];
    float* out = (float*)d_out;
    char*  ws  = (char*)d_ws;

    _Float16* latH = (_Float16*)(ws);                    // 12,582,912 B
    _Float16* latL = (_Float16*)(ws + 12582912);         // 12,582,912 B
    _Float16* forH = (_Float16*)(ws + 25165824);         //  4,194,304 B
    _Float16* forL = (_Float16*)(ws + 29360128);         //  4,194,304 B
    float* invn    = (float*)(ws + 33554432);            //    131,072 B
    float* invnC   = (float*)(ws + 33685504);            //     98,304 B
    float* bv1     = (float*)(ws + 33783808);            //    262,144 B
    int*   bi1     = (int*)  (ws + 34045952);            //    262,144 B
    float* bv2     = (float*)(ws + 34308096);            //    262,144 B
    int*   bfin    = (int*)  (ws + 34570240);            //     32,768 B
    int*   pidx    = (int*)  (ws + 34603008);            //      4,096 B
    int*   qinv    = (int*)  (ws + 34607104);            //     16,384 B
    int*   pinv    = (int*)  (ws + 34623488);            //     16,384 B
    int*   cnt     = (int*)  (ws + 34639872);            //         32 B
    int*   fixrows = (int*)  (ws + 34639904);            //      2,048 B
    float* fixv    = (float*)(ws + 34641952);            //      8,192 B
    int*   fixi    = (int*)  (ws + 34650144);            //      8,192 B

    k_build<<<1, 1024, 0, stream>>>(mask, pidx, qinv, pinv, cnt);
    k_prep<<<2048, 256, 0, stream>>>(x, pinv, qinv, latH, latL, forH, forL, invn, invnC, out);
    k_gemm<<<dim3(4, QG, BZc), 512, 0, stream>>>(latH, latL, forH, forL, invnC, bv1, bi1, bv2);
    k_reduce<<<(BZc * NP + 255) / 256, 256, 0, stream>>>(bv1, bi1, bv2, bfin, cnt, fixrows);
    k_fixA<<<dim3(4, FIXSLOTS, BZc), 256, 0, stream>>>(x, pidx, mask, invn, cnt, fixrows, fixv, fixi);
    k_fixB<<<1, 512, 0, stream>>>(cnt, fixrows, fixv, fixi, qinv, bfin);
    k_scatter<<<dim3(32, BZc), 256, 0, stream>>>(latH, latL, bfin, pidx, out);
}